// Round 5
// baseline (607.141 us; speedup 1.0000x reference)
//
#include <hip/hip_runtime.h>
#include <math.h>

#define NN 30000
#define NE 480000
#define NB 118  // ceil(NN/256)

__device__ __forceinline__ float lrelu(float v) { return v > 0.0f ? v : v * 0.02f; }

__device__ __forceinline__ float4 fma4(float4 v, float w, float4 a) {
    a.x = fmaf(v.x, w, a.x);
    a.y = fmaf(v.y, w, a.y);
    a.z = fmaf(v.z, w, a.z);
    a.w = fmaf(v.w, w, a.w);
    return a;
}

// ---------------- CSR build ----------------

__global__ void k_count(const int* __restrict__ ei, int* __restrict__ cnt) {
    int e = blockIdx.x * 256 + threadIdx.x;
    if (e < NE) atomicAdd(&cnt[ei[NE + e]], 1);
}

__global__ void k_scan1(const int* __restrict__ cnt, int* __restrict__ bsum,
                        float* __restrict__ dinv) {
    __shared__ int sd[256];
    int tid = threadIdx.x;
    int i = blockIdx.x * 256 + tid;
    int v = (i < NN) ? cnt[i] : 0;
    if (i < NN) dinv[i] = 1.0f / sqrtf((float)(v + 1));  // +1 self loop
    sd[tid] = v;
    __syncthreads();
    for (int off = 128; off > 0; off >>= 1) {
        if (tid < off) sd[tid] += sd[tid + off];
        __syncthreads();
    }
    if (tid == 0) bsum[blockIdx.x] = sd[0];
}

__global__ void k_scan2(const int* __restrict__ bsum, int* __restrict__ boff) {
    __shared__ int sd[128];
    int tid = threadIdx.x;  // 128 threads >= NB
    int v = (tid < NB) ? bsum[tid] : 0;
    sd[tid] = v;
    __syncthreads();
    for (int off = 1; off < 128; off <<= 1) {
        int t = (tid >= off) ? sd[tid - off] : 0;
        __syncthreads();
        sd[tid] += t;
        __syncthreads();
    }
    if (tid < NB) boff[tid] = sd[tid] - v;  // exclusive
}

__global__ void k_scan3(const int* __restrict__ cnt, const int* __restrict__ boff,
                        int* __restrict__ row_ptr, int* __restrict__ cursor) {
    __shared__ int sd[256];
    int tid = threadIdx.x;
    int i = blockIdx.x * 256 + tid;
    int v = (i < NN) ? cnt[i] : 0;
    sd[tid] = v;
    __syncthreads();
    for (int off = 1; off < 256; off <<= 1) {
        int t = (tid >= off) ? sd[tid - off] : 0;
        __syncthreads();
        sd[tid] += t;
        __syncthreads();
    }
    if (i < NN) {
        int excl = boff[blockIdx.x] + sd[tid] - v;
        row_ptr[i] = excl;
        cursor[i] = excl;
        if (i == NN - 1) row_ptr[NN] = excl + v;
    }
}

__global__ void k_fill(const int* __restrict__ ei, const float* __restrict__ dinv,
                       int* __restrict__ cursor, int2* __restrict__ csr) {
    int e = blockIdx.x * 256 + threadIdx.x;
    if (e < NE) {
        int s = ei[e];
        int d = ei[NE + e];
        int pos = atomicAdd(&cursor[d], 1);
        float w = dinv[s] * dinv[d];
        csr[pos] = make_int2(s, __float_as_int(w));
    }
}

// ---------------- aggregation: out = D^-1/2 (A+I) D^-1/2 * h ----------------
// h is post-activation. Edge loop unrolled x8, 8 independent accumulators -> 8
// outstanding 16B gathers per thread to cover ~500cy L2/L3 latency.

template <int C>
__launch_bounds__(256)
__global__ void k_agg(const float* __restrict__ h, const int* __restrict__ row_ptr,
                      const int2* __restrict__ csr, const float* __restrict__ dinv,
                      float* __restrict__ out) {
    constexpr int TPN = C / 4;        // threads per node (float4 each)
    constexpr int NPB = 256 / TPN;    // nodes per block
    int node = blockIdx.x * NPB + threadIdx.x / TPN;
    if (node >= NN) return;
    int c = (threadIdx.x % TPN) * 4;
    float di = dinv[node];
    float w0 = di * di;
    float4 hv = *(const float4*)&h[(size_t)node * C + c];
    float4 acc[8];
    acc[0] = make_float4(hv.x * w0, hv.y * w0, hv.z * w0, hv.w * w0);
    #pragma unroll
    for (int j = 1; j < 8; j++) acc[j] = make_float4(0.f, 0.f, 0.f, 0.f);

    int e = row_ptr[node];
    int e1 = row_ptr[node + 1];
    for (; e + 8 <= e1; e += 8) {
        int2 sw[8];
        #pragma unroll
        for (int j = 0; j < 8; j++) sw[j] = csr[e + j];
        float4 v[8];
        #pragma unroll
        for (int j = 0; j < 8; j++) v[j] = *(const float4*)&h[(size_t)sw[j].x * C + c];
        #pragma unroll
        for (int j = 0; j < 8; j++) acc[j] = fma4(v[j], __int_as_float(sw[j].y), acc[j]);
    }
    for (; e + 4 <= e1; e += 4) {
        int2 sw[4];
        #pragma unroll
        for (int j = 0; j < 4; j++) sw[j] = csr[e + j];
        float4 v[4];
        #pragma unroll
        for (int j = 0; j < 4; j++) v[j] = *(const float4*)&h[(size_t)sw[j].x * C + c];
        #pragma unroll
        for (int j = 0; j < 4; j++) acc[j] = fma4(v[j], __int_as_float(sw[j].y), acc[j]);
    }
    for (; e < e1; ++e) {
        int2 sw = csr[e];
        float4 v = *(const float4*)&h[(size_t)sw.x * C + c];
        acc[0] = fma4(v, __int_as_float(sw.y), acc[0]);
    }
    #pragma unroll
    for (int j = 1; j < 8; j++) {
        acc[0].x += acc[j].x;
        acc[0].y += acc[j].y;
        acc[0].z += acc[j].z;
        acc[0].w += acc[j].w;
    }
    *(float4*)&out[(size_t)node * C + c] = acc[0];
}

// ---------------- fp32 GEMM: out[N,128] = lrelu(A[N,K] @ W[K,128] + b) ----------------
// 64-row tile, thread computes 8 rows x 4 cols. LDS: W 64-k chunk (32KB) +
// A 64x64 chunk (16KB) = 48KB -> 3 blocks/CU. Per k-step/wave: 32 FMA vs 3 b128.

template <int K>
__launch_bounds__(256)
__global__ void k_gemm(const float* __restrict__ A, const float* __restrict__ W,
                       const float* __restrict__ bias, float* __restrict__ out) {
    __shared__ float Ws[64 * 128];   // Ws[k][n] chunk, 32 KB
    __shared__ float hs[64 * 64];    // hs[row][k] chunk, 16 KB
    int tid = threadIdx.x;
    int row0 = blockIdx.x * 64;
    int tx = tid & 31;               // col group: cols tx*4 .. tx*4+3
    int ty = tid >> 5;               // row group: rows ty*8 .. ty*8+7

    float4 acc[8];
    #pragma unroll
    for (int i = 0; i < 8; i++) acc[i] = make_float4(0.f, 0.f, 0.f, 0.f);

    for (int kb = 0; kb < K; kb += 64) {
        __syncthreads();
        // stage W chunk: 64x128 = 2048 float4
        for (int i = tid; i < 2048; i += 256)
            *(float4*)&Ws[i * 4] = *(const float4*)&W[(size_t)kb * 128 + i * 4];
        // stage A chunk: 64 rows x 64 ks = 1024 float4 (16 float4 per row)
        for (int i = tid; i < 1024; i += 256) {
            int r = i >> 4;
            int kk = (i & 15) * 4;
            int gr = row0 + r;
            float4 v = (gr < NN) ? *(const float4*)&A[(size_t)gr * K + kb + kk]
                                 : make_float4(0.f, 0.f, 0.f, 0.f);
            *(float4*)&hs[r * 64 + kk] = v;
        }
        __syncthreads();

        #pragma unroll
        for (int k0 = 0; k0 < 64; k0 += 4) {
            float4 wr[4];
            #pragma unroll
            for (int j = 0; j < 4; j++) wr[j] = *(const float4*)&Ws[(k0 + j) * 128 + tx * 4];
            #pragma unroll
            for (int i = 0; i < 8; i++) {
                float4 a = *(const float4*)&hs[(ty * 8 + i) * 64 + k0];  // wave-broadcast
                acc[i].x = fmaf(a.x, wr[0].x, acc[i].x);
                acc[i].y = fmaf(a.x, wr[0].y, acc[i].y);
                acc[i].z = fmaf(a.x, wr[0].z, acc[i].z);
                acc[i].w = fmaf(a.x, wr[0].w, acc[i].w);
                acc[i].x = fmaf(a.y, wr[1].x, acc[i].x);
                acc[i].y = fmaf(a.y, wr[1].y, acc[i].y);
                acc[i].z = fmaf(a.y, wr[1].z, acc[i].z);
                acc[i].w = fmaf(a.y, wr[1].w, acc[i].w);
                acc[i].x = fmaf(a.z, wr[2].x, acc[i].x);
                acc[i].y = fmaf(a.z, wr[2].y, acc[i].y);
                acc[i].z = fmaf(a.z, wr[2].z, acc[i].z);
                acc[i].w = fmaf(a.z, wr[2].w, acc[i].w);
                acc[i].x = fmaf(a.w, wr[3].x, acc[i].x);
                acc[i].y = fmaf(a.w, wr[3].y, acc[i].y);
                acc[i].z = fmaf(a.w, wr[3].z, acc[i].z);
                acc[i].w = fmaf(a.w, wr[3].w, acc[i].w);
            }
        }
    }

    float4 bv = *(const float4*)&bias[tx * 4];
    #pragma unroll
    for (int i = 0; i < 8; i++) {
        int gr = row0 + ty * 8 + i;
        if (gr < NN) {
            float4 r = make_float4(lrelu(acc[i].x + bv.x), lrelu(acc[i].y + bv.y),
                                   lrelu(acc[i].z + bv.z), lrelu(acc[i].w + bv.w));
            *(float4*)&out[(size_t)gr * 128 + tx * 4] = r;
        }
    }
}

// ---------------- final: u = h @ Wout[128,3]  (h already post-activation) ----------------

__launch_bounds__(256)
__global__ void k_out_gemm(const float* __restrict__ h, const float* __restrict__ Wout,
                           float* __restrict__ u) {
    __shared__ float Ws[128 * 3];
    int tid = threadIdx.x;
    for (int i = tid; i < 384; i += 256) Ws[i] = Wout[i];
    __syncthreads();
    int row = blockIdx.x * 8 + (tid >> 5);
    int lane = tid & 31;
    if (row >= NN) return;
    float4 v = *(const float4*)&h[(size_t)row * 128 + lane * 4];
    int k = lane * 4;
    float a0 = v.x * Ws[k * 3 + 0] + v.y * Ws[(k + 1) * 3 + 0] +
               v.z * Ws[(k + 2) * 3 + 0] + v.w * Ws[(k + 3) * 3 + 0];
    float a1 = v.x * Ws[k * 3 + 1] + v.y * Ws[(k + 1) * 3 + 1] +
               v.z * Ws[(k + 2) * 3 + 1] + v.w * Ws[(k + 3) * 3 + 1];
    float a2 = v.x * Ws[k * 3 + 2] + v.y * Ws[(k + 1) * 3 + 2] +
               v.z * Ws[(k + 2) * 3 + 2] + v.w * Ws[(k + 3) * 3 + 2];
    for (int off = 16; off > 0; off >>= 1) {
        a0 += __shfl_down(a0, off, 32);
        a1 += __shfl_down(a1, off, 32);
        a2 += __shfl_down(a2, off, 32);
    }
    if (lane == 0) {
        u[(size_t)row * 3 + 0] = a0;
        u[(size_t)row * 3 + 1] = a1;
        u[(size_t)row * 3 + 2] = a2;
    }
}

// ---------------- final aggregate (3 ch) + bias + tanh*0.5 ----------------

__global__ void k_agg_out(const float* __restrict__ u, const int* __restrict__ row_ptr,
                          const int2* __restrict__ csr, const float* __restrict__ dinv,
                          const float* __restrict__ bout, float* __restrict__ out) {
    int node = blockIdx.x * 256 + threadIdx.x;
    if (node >= NN) return;
    float di = dinv[node], w0 = di * di;
    float s0 = u[(size_t)node * 3 + 0] * w0;
    float s1 = u[(size_t)node * 3 + 1] * w0;
    float s2 = u[(size_t)node * 3 + 2] * w0;
    float b0a = 0.f, b1a = 0.f, b2a = 0.f;
    int e = row_ptr[node];
    int e1 = row_ptr[node + 1];
    for (; e + 2 <= e1; e += 2) {
        int2 swa = csr[e], swb = csr[e + 1];
        float wa = __int_as_float(swa.y), wb = __int_as_float(swb.y);
        const float* ua = &u[(size_t)swa.x * 3];
        const float* ub = &u[(size_t)swb.x * 3];
        s0 = fmaf(ua[0], wa, s0);
        s1 = fmaf(ua[1], wa, s1);
        s2 = fmaf(ua[2], wa, s2);
        b0a = fmaf(ub[0], wb, b0a);
        b1a = fmaf(ub[1], wb, b1a);
        b2a = fmaf(ub[2], wb, b2a);
    }
    for (; e < e1; ++e) {
        int2 sw = csr[e];
        float w = __int_as_float(sw.y);
        const float* us = &u[(size_t)sw.x * 3];
        s0 = fmaf(us[0], w, s0);
        s1 = fmaf(us[1], w, s1);
        s2 = fmaf(us[2], w, s2);
    }
    out[(size_t)node * 3 + 0] = tanhf(s0 + b0a + bout[0]) * 0.5f;
    out[(size_t)node * 3 + 1] = tanhf(s1 + b1a + bout[1]) * 0.5f;
    out[(size_t)node * 3 + 2] = tanhf(s2 + b2a + bout[2]) * 0.5f;
}

// ---------------- launch ----------------

extern "C" void kernel_launch(void* const* d_in, const int* in_sizes, int n_in,
                              void* d_out, int out_size, void* d_ws, size_t ws_size,
                              hipStream_t stream) {
    const float* x        = (const float*)d_in[0];
    const int*   ei       = (const int*)d_in[1];   // int32: [2, NE] row-major
    const float* W0       = (const float*)d_in[2];
    const float* b0       = (const float*)d_in[3];
    const float* Wh       = (const float*)d_in[4];
    const float* bh       = (const float*)d_in[5];
    const float* Wout     = (const float*)d_in[6];
    const float* bout     = (const float*)d_in[7];
    float* out            = (float*)d_out;

    char* ws = (char*)d_ws;
    float* bufA   = (float*)(ws + 0);              // NN*128 floats = 15,360,000 B
    float* bufB   = (float*)(ws + 15360000);       // NN*128 floats
    float* dinv   = (float*)(ws + 30720000);       // NN floats
    int*   cnt    = (int*)  (ws + 30840000);       // NN ints
    int*   row_ptr= (int*)  (ws + 30960000);       // NN+1 ints (padded)
    int*   cursor = (int*)  (ws + 31080064);       // NN ints
    int2*  csr    = (int2*) (ws + 31200064);       // NE int2 = 3,840,000 B

    // scan temporaries: borrow bufA space (unused until after CSR build)
    int* bsum = (int*)bufA;        // NB ints
    int* boff = bsum + 256;        // NB ints

    hipMemsetAsync(cnt, 0, NN * sizeof(int), stream);
    k_count<<<(NE + 255) / 256, 256, 0, stream>>>(ei, cnt);
    k_scan1<<<NB, 256, 0, stream>>>(cnt, bsum, dinv);
    k_scan2<<<1, 128, 0, stream>>>(bsum, boff);
    k_scan3<<<NB, 256, 0, stream>>>(cnt, boff, row_ptr, cursor);
    k_fill<<<(NE + 255) / 256, 256, 0, stream>>>(ei, dinv, cursor, csr);

    // layer 0: h1 = lrelu((A_hat x) @ W0 + b0)   (aggregate-first: 64ch gather; x is raw)
    k_agg<64><<<NN / 16, 256, 0, stream>>>(x, row_ptr, csr, dinv, bufA);
    k_gemm<64><<<(NN + 63) / 64, 256, 0, stream>>>(bufA, W0, b0, bufB);

    // hidden layers: h = lrelu((A_hat h) @ Wh[i] + bh[i])   (h already activated)
    for (int i = 0; i < 6; i++) {
        k_agg<128><<<NN / 8, 256, 0, stream>>>(bufB, row_ptr, csr, dinv, bufA);
        k_gemm<128><<<(NN + 63) / 64, 256, 0, stream>>>(bufA, Wh + (size_t)i * 128 * 128,
                                                        bh + (size_t)i * 128, bufB);
    }

    // final: out = tanh(A_hat (h @ Wout) + bout) * 0.5   (GEMM-first: 3ch gather)
    k_out_gemm<<<(NN + 7) / 8, 256, 0, stream>>>(bufB, Wout, bufA /* u: NN x 3 */);
    k_agg_out<<<(NN + 255) / 256, 256, 0, stream>>>(bufA, row_ptr, csr, dinv, bout, out);
}

// Round 6
// 538.680 us; speedup vs baseline: 1.1271x; 1.1271x over previous
//
#include <hip/hip_runtime.h>
#include <math.h>

#define NN 30000
#define NE 480000
#define NB 118  // ceil(NN/256)

__device__ __forceinline__ float lrelu(float v) { return v > 0.0f ? v : v * 0.02f; }

__device__ __forceinline__ float4 fma4(float4 v, float w, float4 a) {
    a.x = fmaf(v.x, w, a.x);
    a.y = fmaf(v.y, w, a.y);
    a.z = fmaf(v.z, w, a.z);
    a.w = fmaf(v.w, w, a.w);
    return a;
}

// ---------------- CSR build ----------------

__global__ void k_count(const int* __restrict__ ei, int* __restrict__ cnt) {
    int e = blockIdx.x * 256 + threadIdx.x;
    if (e < NE) atomicAdd(&cnt[ei[NE + e]], 1);
}

__global__ void k_scan1(const int* __restrict__ cnt, int* __restrict__ bsum,
                        float* __restrict__ dinv) {
    __shared__ int sd[256];
    int tid = threadIdx.x;
    int i = blockIdx.x * 256 + tid;
    int v = (i < NN) ? cnt[i] : 0;
    if (i < NN) dinv[i] = 1.0f / sqrtf((float)(v + 1));  // +1 self loop
    sd[tid] = v;
    __syncthreads();
    for (int off = 128; off > 0; off >>= 1) {
        if (tid < off) sd[tid] += sd[tid + off];
        __syncthreads();
    }
    if (tid == 0) bsum[blockIdx.x] = sd[0];
}

__global__ void k_scan2(const int* __restrict__ bsum, int* __restrict__ boff) {
    __shared__ int sd[128];
    int tid = threadIdx.x;  // 128 threads >= NB
    int v = (tid < NB) ? bsum[tid] : 0;
    sd[tid] = v;
    __syncthreads();
    for (int off = 1; off < 128; off <<= 1) {
        int t = (tid >= off) ? sd[tid - off] : 0;
        __syncthreads();
        sd[tid] += t;
        __syncthreads();
    }
    if (tid < NB) boff[tid] = sd[tid] - v;  // exclusive
}

__global__ void k_scan3(const int* __restrict__ cnt, const int* __restrict__ boff,
                        int* __restrict__ row_ptr, int* __restrict__ cursor) {
    __shared__ int sd[256];
    int tid = threadIdx.x;
    int i = blockIdx.x * 256 + tid;
    int v = (i < NN) ? cnt[i] : 0;
    sd[tid] = v;
    __syncthreads();
    for (int off = 1; off < 256; off <<= 1) {
        int t = (tid >= off) ? sd[tid - off] : 0;
        __syncthreads();
        sd[tid] += t;
        __syncthreads();
    }
    if (i < NN) {
        int excl = boff[blockIdx.x] + sd[tid] - v;
        row_ptr[i] = excl;
        cursor[i] = excl;
        if (i == NN - 1) row_ptr[NN] = excl + v;
    }
}

__global__ void k_fill(const int* __restrict__ ei, const float* __restrict__ dinv,
                       int* __restrict__ cursor, int2* __restrict__ csr) {
    int e = blockIdx.x * 256 + threadIdx.x;
    if (e < NE) {
        int s = ei[e];
        int d = ei[NE + e];
        int pos = atomicAdd(&cursor[d], 1);
        float w = dinv[s] * dinv[d];
        csr[pos] = make_int2(s, __float_as_int(w));
    }
}

// ---------------- aggregation: out = D^-1/2 (A+I) D^-1/2 * h ----------------
// h is post-activation. Edge loop unrolled x8, 8 independent accumulators -> 8
// outstanding 16B gathers per thread to cover L2/L3 latency. VGPR ~80, no spill.

template <int C>
__launch_bounds__(256)
__global__ void k_agg(const float* __restrict__ h, const int* __restrict__ row_ptr,
                      const int2* __restrict__ csr, const float* __restrict__ dinv,
                      float* __restrict__ out) {
    constexpr int TPN = C / 4;        // threads per node (float4 each)
    constexpr int NPB = 256 / TPN;    // nodes per block
    int node = blockIdx.x * NPB + threadIdx.x / TPN;
    if (node >= NN) return;
    int c = (threadIdx.x % TPN) * 4;
    float di = dinv[node];
    float w0 = di * di;
    float4 hv = *(const float4*)&h[(size_t)node * C + c];
    float4 acc[8];
    acc[0] = make_float4(hv.x * w0, hv.y * w0, hv.z * w0, hv.w * w0);
    #pragma unroll
    for (int j = 1; j < 8; j++) acc[j] = make_float4(0.f, 0.f, 0.f, 0.f);

    int e = row_ptr[node];
    int e1 = row_ptr[node + 1];
    for (; e + 8 <= e1; e += 8) {
        int2 sw[8];
        #pragma unroll
        for (int j = 0; j < 8; j++) sw[j] = csr[e + j];
        float4 v[8];
        #pragma unroll
        for (int j = 0; j < 8; j++) v[j] = *(const float4*)&h[(size_t)sw[j].x * C + c];
        #pragma unroll
        for (int j = 0; j < 8; j++) acc[j] = fma4(v[j], __int_as_float(sw[j].y), acc[j]);
    }
    for (; e + 4 <= e1; e += 4) {
        int2 sw[4];
        #pragma unroll
        for (int j = 0; j < 4; j++) sw[j] = csr[e + j];
        float4 v[4];
        #pragma unroll
        for (int j = 0; j < 4; j++) v[j] = *(const float4*)&h[(size_t)sw[j].x * C + c];
        #pragma unroll
        for (int j = 0; j < 4; j++) acc[j] = fma4(v[j], __int_as_float(sw[j].y), acc[j]);
    }
    for (; e < e1; ++e) {
        int2 sw = csr[e];
        float4 v = *(const float4*)&h[(size_t)sw.x * C + c];
        acc[0] = fma4(v, __int_as_float(sw.y), acc[0]);
    }
    #pragma unroll
    for (int j = 1; j < 8; j++) {
        acc[0].x += acc[j].x;
        acc[0].y += acc[j].y;
        acc[0].z += acc[j].z;
        acc[0].w += acc[j].w;
    }
    *(float4*)&out[(size_t)node * C + c] = acc[0];
}

// ---------------- fp32 GEMM: out[N,128] = lrelu(A[N,K] @ W[K,128] + b) ----------------
// 32-row tile, thread computes 4 rows x 4 cols. Proven no-spill shape (round 4).
// // 64-row/8-acc variant spilled (VGPR=256, 139MB scratch writes) — do not revisit
// // without cutting temps. Keep acc at 16 VGPRs + 8 b128 temps.

template <int K>
__launch_bounds__(256)
__global__ void k_gemm(const float* __restrict__ A, const float* __restrict__ W,
                       const float* __restrict__ bias, float* __restrict__ out) {
    __shared__ float Ws[64 * 128];   // one 64-k chunk of W
    __shared__ float hs[32 * K];     // 32-row tile of A
    constexpr int K4 = K / 4;
    int tid = threadIdx.x;
    int row0 = blockIdx.x * 32;

    for (int i = tid; i < 32 * K4; i += 256) {
        int r = i / K4;
        int gr = row0 + r;
        float4 v = (gr < NN) ? *(const float4*)&A[(size_t)gr * K + (i % K4) * 4]
                             : make_float4(0.f, 0.f, 0.f, 0.f);
        *(float4*)&hs[i * 4] = v;
    }

    int tx = tid & 31, ty = tid >> 5;
    float4 acc[4];
    #pragma unroll
    for (int i = 0; i < 4; i++) acc[i] = make_float4(0.f, 0.f, 0.f, 0.f);

    for (int kb = 0; kb < K; kb += 64) {
        __syncthreads();
        for (int i = tid; i < 64 * 32; i += 256)
            *(float4*)&Ws[i * 4] = *(const float4*)&W[(size_t)kb * 128 + i * 4];
        __syncthreads();

        #pragma unroll
        for (int k0 = 0; k0 < 64; k0 += 4) {
            float4 hr[4], wr[4];
            #pragma unroll
            for (int i = 0; i < 4; i++) hr[i] = *(const float4*)&hs[(ty * 4 + i) * K + kb + k0];
            #pragma unroll
            for (int j = 0; j < 4; j++) wr[j] = *(const float4*)&Ws[(k0 + j) * 128 + tx * 4];
            #pragma unroll
            for (int i = 0; i < 4; i++) {
                acc[i].x = fmaf(hr[i].x, wr[0].x, acc[i].x);
                acc[i].y = fmaf(hr[i].x, wr[0].y, acc[i].y);
                acc[i].z = fmaf(hr[i].x, wr[0].z, acc[i].z);
                acc[i].w = fmaf(hr[i].x, wr[0].w, acc[i].w);
                acc[i].x = fmaf(hr[i].y, wr[1].x, acc[i].x);
                acc[i].y = fmaf(hr[i].y, wr[1].y, acc[i].y);
                acc[i].z = fmaf(hr[i].y, wr[1].z, acc[i].z);
                acc[i].w = fmaf(hr[i].y, wr[1].w, acc[i].w);
                acc[i].x = fmaf(hr[i].z, wr[2].x, acc[i].x);
                acc[i].y = fmaf(hr[i].z, wr[2].y, acc[i].y);
                acc[i].z = fmaf(hr[i].z, wr[2].z, acc[i].z);
                acc[i].w = fmaf(hr[i].z, wr[2].w, acc[i].w);
                acc[i].x = fmaf(hr[i].w, wr[3].x, acc[i].x);
                acc[i].y = fmaf(hr[i].w, wr[3].y, acc[i].y);
                acc[i].z = fmaf(hr[i].w, wr[3].z, acc[i].z);
                acc[i].w = fmaf(hr[i].w, wr[3].w, acc[i].w);
            }
        }
    }

    float4 bv = *(const float4*)&bias[tx * 4];
    #pragma unroll
    for (int i = 0; i < 4; i++) {
        int gr = row0 + ty * 4 + i;
        if (gr < NN) {
            float4 r = make_float4(lrelu(acc[i].x + bv.x), lrelu(acc[i].y + bv.y),
                                   lrelu(acc[i].z + bv.z), lrelu(acc[i].w + bv.w));
            *(float4*)&out[(size_t)gr * 128 + tx * 4] = r;
        }
    }
}

// ---------------- final: u = h @ Wout[128,3]  (h already post-activation) ----------------

__launch_bounds__(256)
__global__ void k_out_gemm(const float* __restrict__ h, const float* __restrict__ Wout,
                           float* __restrict__ u) {
    __shared__ float Ws[128 * 3];
    int tid = threadIdx.x;
    for (int i = tid; i < 384; i += 256) Ws[i] = Wout[i];
    __syncthreads();
    int row = blockIdx.x * 8 + (tid >> 5);
    int lane = tid & 31;
    if (row >= NN) return;
    float4 v = *(const float4*)&h[(size_t)row * 128 + lane * 4];
    int k = lane * 4;
    float a0 = v.x * Ws[k * 3 + 0] + v.y * Ws[(k + 1) * 3 + 0] +
               v.z * Ws[(k + 2) * 3 + 0] + v.w * Ws[(k + 3) * 3 + 0];
    float a1 = v.x * Ws[k * 3 + 1] + v.y * Ws[(k + 1) * 3 + 1] +
               v.z * Ws[(k + 2) * 3 + 1] + v.w * Ws[(k + 3) * 3 + 1];
    float a2 = v.x * Ws[k * 3 + 2] + v.y * Ws[(k + 1) * 3 + 2] +
               v.z * Ws[(k + 2) * 3 + 2] + v.w * Ws[(k + 3) * 3 + 2];
    for (int off = 16; off > 0; off >>= 1) {
        a0 += __shfl_down(a0, off, 32);
        a1 += __shfl_down(a1, off, 32);
        a2 += __shfl_down(a2, off, 32);
    }
    if (lane == 0) {
        u[(size_t)row * 3 + 0] = a0;
        u[(size_t)row * 3 + 1] = a1;
        u[(size_t)row * 3 + 2] = a2;
    }
}

// ---------------- final aggregate (3 ch) + bias + tanh*0.5 ----------------

__global__ void k_agg_out(const float* __restrict__ u, const int* __restrict__ row_ptr,
                          const int2* __restrict__ csr, const float* __restrict__ dinv,
                          const float* __restrict__ bout, float* __restrict__ out) {
    int node = blockIdx.x * 256 + threadIdx.x;
    if (node >= NN) return;
    float di = dinv[node], w0 = di * di;
    float s0 = u[(size_t)node * 3 + 0] * w0;
    float s1 = u[(size_t)node * 3 + 1] * w0;
    float s2 = u[(size_t)node * 3 + 2] * w0;
    float b0a = 0.f, b1a = 0.f, b2a = 0.f;
    int e = row_ptr[node];
    int e1 = row_ptr[node + 1];
    for (; e + 2 <= e1; e += 2) {
        int2 swa = csr[e], swb = csr[e + 1];
        float wa = __int_as_float(swa.y), wb = __int_as_float(swb.y);
        const float* ua = &u[(size_t)swa.x * 3];
        const float* ub = &u[(size_t)swb.x * 3];
        s0 = fmaf(ua[0], wa, s0);
        s1 = fmaf(ua[1], wa, s1);
        s2 = fmaf(ua[2], wa, s2);
        b0a = fmaf(ub[0], wb, b0a);
        b1a = fmaf(ub[1], wb, b1a);
        b2a = fmaf(ub[2], wb, b2a);
    }
    for (; e < e1; ++e) {
        int2 sw = csr[e];
        float w = __int_as_float(sw.y);
        const float* us = &u[(size_t)sw.x * 3];
        s0 = fmaf(us[0], w, s0);
        s1 = fmaf(us[1], w, s1);
        s2 = fmaf(us[2], w, s2);
    }
    out[(size_t)node * 3 + 0] = tanhf(s0 + b0a + bout[0]) * 0.5f;
    out[(size_t)node * 3 + 1] = tanhf(s1 + b1a + bout[1]) * 0.5f;
    out[(size_t)node * 3 + 2] = tanhf(s2 + b2a + bout[2]) * 0.5f;
}

// ---------------- launch ----------------

extern "C" void kernel_launch(void* const* d_in, const int* in_sizes, int n_in,
                              void* d_out, int out_size, void* d_ws, size_t ws_size,
                              hipStream_t stream) {
    const float* x        = (const float*)d_in[0];
    const int*   ei       = (const int*)d_in[1];   // int32: [2, NE] row-major
    const float* W0       = (const float*)d_in[2];
    const float* b0       = (const float*)d_in[3];
    const float* Wh       = (const float*)d_in[4];
    const float* bh       = (const float*)d_in[5];
    const float* Wout     = (const float*)d_in[6];
    const float* bout     = (const float*)d_in[7];
    float* out            = (float*)d_out;

    char* ws = (char*)d_ws;
    float* bufA   = (float*)(ws + 0);              // NN*128 floats = 15,360,000 B
    float* bufB   = (float*)(ws + 15360000);       // NN*128 floats
    float* dinv   = (float*)(ws + 30720000);       // NN floats
    int*   cnt    = (int*)  (ws + 30840000);       // NN ints
    int*   row_ptr= (int*)  (ws + 30960000);       // NN+1 ints (padded)
    int*   cursor = (int*)  (ws + 31080064);       // NN ints
    int2*  csr    = (int2*) (ws + 31200064);       // NE int2 = 3,840,000 B

    // scan temporaries: borrow bufA space (unused until after CSR build)
    int* bsum = (int*)bufA;        // NB ints
    int* boff = bsum + 256;        // NB ints

    hipMemsetAsync(cnt, 0, NN * sizeof(int), stream);
    k_count<<<(NE + 255) / 256, 256, 0, stream>>>(ei, cnt);
    k_scan1<<<NB, 256, 0, stream>>>(cnt, bsum, dinv);
    k_scan2<<<1, 128, 0, stream>>>(bsum, boff);
    k_scan3<<<NB, 256, 0, stream>>>(cnt, boff, row_ptr, cursor);
    k_fill<<<(NE + 255) / 256, 256, 0, stream>>>(ei, dinv, cursor, csr);

    // layer 0: h1 = lrelu((A_hat x) @ W0 + b0)   (aggregate-first: 64ch gather; x is raw)
    k_agg<64><<<NN / 16, 256, 0, stream>>>(x, row_ptr, csr, dinv, bufA);
    k_gemm<64><<<(NN + 31) / 32, 256, 0, stream>>>(bufA, W0, b0, bufB);

    // hidden layers: h = lrelu((A_hat h) @ Wh[i] + bh[i])   (h already activated)
    for (int i = 0; i < 6; i++) {
        k_agg<128><<<NN / 8, 256, 0, stream>>>(bufB, row_ptr, csr, dinv, bufA);
        k_gemm<128><<<(NN + 31) / 32, 256, 0, stream>>>(bufA, Wh + (size_t)i * 128 * 128,
                                                        bh + (size_t)i * 128, bufB);
    }

    // final: out = tanh(A_hat (h @ Wout) + bout) * 0.5   (GEMM-first: 3ch gather)
    k_out_gemm<<<(NN + 7) / 8, 256, 0, stream>>>(bufB, Wout, bufA /* u: NN x 3 */);
    k_agg_out<<<(NN + 255) / 256, 256, 0, stream>>>(bufA, row_ptr, csr, dinv, bout, out);
}

// Round 7
// 496.418 us; speedup vs baseline: 1.2230x; 1.0851x over previous
//
#include <hip/hip_runtime.h>
#include <hip/hip_fp16.h>
#include <math.h>

#define NN 30000
#define NE 480000
#define NB 118  // ceil(NN/256)

__device__ __forceinline__ float lrelu(float v) { return v > 0.0f ? v : v * 0.02f; }

__device__ __forceinline__ float4 fma4(float4 v, float w, float4 a) {
    a.x = fmaf(v.x, w, a.x);
    a.y = fmaf(v.y, w, a.y);
    a.z = fmaf(v.z, w, a.z);
    a.w = fmaf(v.w, w, a.w);
    return a;
}

// load 4 consecutive halfs -> float4 (8B load)
__device__ __forceinline__ float4 loadh4(const __half* p) {
    uint2 raw = *(const uint2*)p;
    __half2 h0 = *(__half2*)&raw.x;
    __half2 h1 = *(__half2*)&raw.y;
    float2 f0 = __half22float2(h0);
    float2 f1 = __half22float2(h1);
    return make_float4(f0.x, f0.y, f1.x, f1.y);
}

// pack float4 -> 4 halfs (8B store)
__device__ __forceinline__ void storeh4(__half* p, float4 v) {
    __half2 a = __floats2half2_rn(v.x, v.y);
    __half2 b = __floats2half2_rn(v.z, v.w);
    uint2 pk;
    pk.x = *(unsigned int*)&a;
    pk.y = *(unsigned int*)&b;
    *(uint2*)p = pk;
}

// ---------------- CSR build ----------------

__global__ void k_count(const int* __restrict__ ei, int* __restrict__ cnt) {
    int e = blockIdx.x * 256 + threadIdx.x;
    if (e < NE) atomicAdd(&cnt[ei[NE + e]], 1);
}

__global__ void k_scan1(const int* __restrict__ cnt, int* __restrict__ bsum,
                        float* __restrict__ dinv) {
    __shared__ int sd[256];
    int tid = threadIdx.x;
    int i = blockIdx.x * 256 + tid;
    int v = (i < NN) ? cnt[i] : 0;
    if (i < NN) dinv[i] = 1.0f / sqrtf((float)(v + 1));  // +1 self loop
    sd[tid] = v;
    __syncthreads();
    for (int off = 128; off > 0; off >>= 1) {
        if (tid < off) sd[tid] += sd[tid + off];
        __syncthreads();
    }
    if (tid == 0) bsum[blockIdx.x] = sd[0];
}

__global__ void k_scan2(const int* __restrict__ bsum, int* __restrict__ boff) {
    __shared__ int sd[128];
    int tid = threadIdx.x;  // 128 threads >= NB
    int v = (tid < NB) ? bsum[tid] : 0;
    sd[tid] = v;
    __syncthreads();
    for (int off = 1; off < 128; off <<= 1) {
        int t = (tid >= off) ? sd[tid - off] : 0;
        __syncthreads();
        sd[tid] += t;
        __syncthreads();
    }
    if (tid < NB) boff[tid] = sd[tid] - v;  // exclusive
}

__global__ void k_scan3(const int* __restrict__ cnt, const int* __restrict__ boff,
                        int* __restrict__ row_ptr, int* __restrict__ cursor) {
    __shared__ int sd[256];
    int tid = threadIdx.x;
    int i = blockIdx.x * 256 + tid;
    int v = (i < NN) ? cnt[i] : 0;
    sd[tid] = v;
    __syncthreads();
    for (int off = 1; off < 256; off <<= 1) {
        int t = (tid >= off) ? sd[tid - off] : 0;
        __syncthreads();
        sd[tid] += t;
        __syncthreads();
    }
    if (i < NN) {
        int excl = boff[blockIdx.x] + sd[tid] - v;
        row_ptr[i] = excl;
        cursor[i] = excl;
        if (i == NN - 1) row_ptr[NN] = excl + v;
    }
}

__global__ void k_fill(const int* __restrict__ ei, const float* __restrict__ dinv,
                       int* __restrict__ cursor, int2* __restrict__ csr) {
    int e = blockIdx.x * 256 + threadIdx.x;
    if (e < NE) {
        int s = ei[e];
        int d = ei[NE + e];
        int pos = atomicAdd(&cursor[d], 1);
        float w = dinv[s] * dinv[d];
        csr[pos] = make_int2(s, __float_as_int(w));
    }
}

// ---------------- fp32 aggregation (layer 0 only: x is fp32, 64 ch) ----------------

template <int C>
__launch_bounds__(256)
__global__ void k_agg(const float* __restrict__ h, const int* __restrict__ row_ptr,
                      const int2* __restrict__ csr, const float* __restrict__ dinv,
                      float* __restrict__ out) {
    constexpr int TPN = C / 4;
    constexpr int NPB = 256 / TPN;
    int node = blockIdx.x * NPB + threadIdx.x / TPN;
    if (node >= NN) return;
    int c = (threadIdx.x % TPN) * 4;
    float di = dinv[node];
    float w0 = di * di;
    float4 hv = *(const float4*)&h[(size_t)node * C + c];
    float4 acc[8];
    acc[0] = make_float4(hv.x * w0, hv.y * w0, hv.z * w0, hv.w * w0);
    #pragma unroll
    for (int j = 1; j < 8; j++) acc[j] = make_float4(0.f, 0.f, 0.f, 0.f);

    int e = row_ptr[node];
    int e1 = row_ptr[node + 1];
    for (; e + 8 <= e1; e += 8) {
        int2 sw[8];
        #pragma unroll
        for (int j = 0; j < 8; j++) sw[j] = csr[e + j];
        float4 v[8];
        #pragma unroll
        for (int j = 0; j < 8; j++) v[j] = *(const float4*)&h[(size_t)sw[j].x * C + c];
        #pragma unroll
        for (int j = 0; j < 8; j++) acc[j] = fma4(v[j], __int_as_float(sw[j].y), acc[j]);
    }
    for (; e < e1; ++e) {
        int2 sw = csr[e];
        float4 v = *(const float4*)&h[(size_t)sw.x * C + c];
        acc[0] = fma4(v, __int_as_float(sw.y), acc[0]);
    }
    #pragma unroll
    for (int j = 1; j < 8; j++) {
        acc[0].x += acc[j].x;
        acc[0].y += acc[j].y;
        acc[0].z += acc[j].z;
        acc[0].w += acc[j].w;
    }
    *(float4*)&out[(size_t)node * C + c] = acc[0];
}

// ---------------- fp16 aggregation (hidden layers): gather h16, accumulate fp32 ----------------
// h16 table is 7.7MB (vs 15.4 fp32): better L2 residency, half the gather bytes.

__launch_bounds__(256)
__global__ void k_agg16(const __half* __restrict__ h, const int* __restrict__ row_ptr,
                        const int2* __restrict__ csr, const float* __restrict__ dinv,
                        float* __restrict__ out) {
    int node = blockIdx.x * 8 + (threadIdx.x >> 5);   // 32 threads/node, C=128
    if (node >= NN) return;
    int c = (threadIdx.x & 31) * 4;
    float di = dinv[node];
    float w0 = di * di;
    float4 hv = loadh4(&h[(size_t)node * 128 + c]);
    float4 acc[8];
    acc[0] = make_float4(hv.x * w0, hv.y * w0, hv.z * w0, hv.w * w0);
    #pragma unroll
    for (int j = 1; j < 8; j++) acc[j] = make_float4(0.f, 0.f, 0.f, 0.f);

    int e = row_ptr[node];
    int e1 = row_ptr[node + 1];
    for (; e + 8 <= e1; e += 8) {
        int2 sw[8];
        #pragma unroll
        for (int j = 0; j < 8; j++) sw[j] = csr[e + j];
        float4 v[8];
        #pragma unroll
        for (int j = 0; j < 8; j++) v[j] = loadh4(&h[(size_t)sw[j].x * 128 + c]);
        #pragma unroll
        for (int j = 0; j < 8; j++) acc[j] = fma4(v[j], __int_as_float(sw[j].y), acc[j]);
    }
    for (; e < e1; ++e) {
        int2 sw = csr[e];
        float4 v = loadh4(&h[(size_t)sw.x * 128 + c]);
        acc[0] = fma4(v, __int_as_float(sw.y), acc[0]);
    }
    #pragma unroll
    for (int j = 1; j < 8; j++) {
        acc[0].x += acc[j].x;
        acc[0].y += acc[j].y;
        acc[0].z += acc[j].z;
        acc[0].w += acc[j].w;
    }
    *(float4*)&out[(size_t)node * 128 + c] = acc[0];
}

// ---------------- fp32 GEMM: out16[N,128] = fp16(lrelu(A[N,K] @ W[K,128] + b)) ----------------
// 32-row tile, thread computes 4 rows x 4 cols. Proven no-spill shape.
// // 64-row/8-acc variant spilled (VGPR=256, 139MB scratch writes) — do not revisit.

template <int K>
__launch_bounds__(256)
__global__ void k_gemm(const float* __restrict__ A, const float* __restrict__ W,
                       const float* __restrict__ bias, __half* __restrict__ out16) {
    __shared__ float Ws[64 * 128];   // one 64-k chunk of W
    __shared__ float hs[32 * K];     // 32-row tile of A
    constexpr int K4 = K / 4;
    int tid = threadIdx.x;
    int row0 = blockIdx.x * 32;

    for (int i = tid; i < 32 * K4; i += 256) {
        int r = i / K4;
        int gr = row0 + r;
        float4 v = (gr < NN) ? *(const float4*)&A[(size_t)gr * K + (i % K4) * 4]
                             : make_float4(0.f, 0.f, 0.f, 0.f);
        *(float4*)&hs[i * 4] = v;
    }

    int tx = tid & 31, ty = tid >> 5;
    float4 acc[4];
    #pragma unroll
    for (int i = 0; i < 4; i++) acc[i] = make_float4(0.f, 0.f, 0.f, 0.f);

    for (int kb = 0; kb < K; kb += 64) {
        __syncthreads();
        for (int i = tid; i < 64 * 32; i += 256)
            *(float4*)&Ws[i * 4] = *(const float4*)&W[(size_t)kb * 128 + i * 4];
        __syncthreads();

        #pragma unroll
        for (int k0 = 0; k0 < 64; k0 += 4) {
            float4 hr[4], wr[4];
            #pragma unroll
            for (int i = 0; i < 4; i++) hr[i] = *(const float4*)&hs[(ty * 4 + i) * K + kb + k0];
            #pragma unroll
            for (int j = 0; j < 4; j++) wr[j] = *(const float4*)&Ws[(k0 + j) * 128 + tx * 4];
            #pragma unroll
            for (int i = 0; i < 4; i++) {
                acc[i].x = fmaf(hr[i].x, wr[0].x, acc[i].x);
                acc[i].y = fmaf(hr[i].x, wr[0].y, acc[i].y);
                acc[i].z = fmaf(hr[i].x, wr[0].z, acc[i].z);
                acc[i].w = fmaf(hr[i].x, wr[0].w, acc[i].w);
                acc[i].x = fmaf(hr[i].y, wr[1].x, acc[i].x);
                acc[i].y = fmaf(hr[i].y, wr[1].y, acc[i].y);
                acc[i].z = fmaf(hr[i].y, wr[1].z, acc[i].z);
                acc[i].w = fmaf(hr[i].y, wr[1].w, acc[i].w);
                acc[i].x = fmaf(hr[i].z, wr[2].x, acc[i].x);
                acc[i].y = fmaf(hr[i].z, wr[2].y, acc[i].y);
                acc[i].z = fmaf(hr[i].z, wr[2].z, acc[i].z);
                acc[i].w = fmaf(hr[i].z, wr[2].w, acc[i].w);
                acc[i].x = fmaf(hr[i].w, wr[3].x, acc[i].x);
                acc[i].y = fmaf(hr[i].w, wr[3].y, acc[i].y);
                acc[i].z = fmaf(hr[i].w, wr[3].z, acc[i].z);
                acc[i].w = fmaf(hr[i].w, wr[3].w, acc[i].w);
            }
        }
    }

    float4 bv = *(const float4*)&bias[tx * 4];
    #pragma unroll
    for (int i = 0; i < 4; i++) {
        int gr = row0 + ty * 4 + i;
        if (gr < NN) {
            float4 r = make_float4(lrelu(acc[i].x + bv.x), lrelu(acc[i].y + bv.y),
                                   lrelu(acc[i].z + bv.z), lrelu(acc[i].w + bv.w));
            storeh4(&out16[(size_t)gr * 128 + tx * 4], r);
        }
    }
}

// ---------------- final: u = h16 @ Wout[128,3] ----------------

__launch_bounds__(256)
__global__ void k_out_gemm(const __half* __restrict__ h, const float* __restrict__ Wout,
                           float* __restrict__ u) {
    __shared__ float Ws[128 * 3];
    int tid = threadIdx.x;
    for (int i = tid; i < 384; i += 256) Ws[i] = Wout[i];
    __syncthreads();
    int row = blockIdx.x * 8 + (tid >> 5);
    int lane = tid & 31;
    if (row >= NN) return;
    float4 v = loadh4(&h[(size_t)row * 128 + lane * 4]);
    int k = lane * 4;
    float a0 = v.x * Ws[k * 3 + 0] + v.y * Ws[(k + 1) * 3 + 0] +
               v.z * Ws[(k + 2) * 3 + 0] + v.w * Ws[(k + 3) * 3 + 0];
    float a1 = v.x * Ws[k * 3 + 1] + v.y * Ws[(k + 1) * 3 + 1] +
               v.z * Ws[(k + 2) * 3 + 1] + v.w * Ws[(k + 3) * 3 + 1];
    float a2 = v.x * Ws[k * 3 + 2] + v.y * Ws[(k + 1) * 3 + 2] +
               v.z * Ws[(k + 2) * 3 + 2] + v.w * Ws[(k + 3) * 3 + 2];
    for (int off = 16; off > 0; off >>= 1) {
        a0 += __shfl_down(a0, off, 32);
        a1 += __shfl_down(a1, off, 32);
        a2 += __shfl_down(a2, off, 32);
    }
    if (lane == 0) {
        u[(size_t)row * 3 + 0] = a0;
        u[(size_t)row * 3 + 1] = a1;
        u[(size_t)row * 3 + 2] = a2;
    }
}

// ---------------- final aggregate (3 ch) + bias + tanh*0.5 ----------------

__global__ void k_agg_out(const float* __restrict__ u, const int* __restrict__ row_ptr,
                          const int2* __restrict__ csr, const float* __restrict__ dinv,
                          const float* __restrict__ bout, float* __restrict__ out) {
    int node = blockIdx.x * 256 + threadIdx.x;
    if (node >= NN) return;
    float di = dinv[node], w0 = di * di;
    float s0 = u[(size_t)node * 3 + 0] * w0;
    float s1 = u[(size_t)node * 3 + 1] * w0;
    float s2 = u[(size_t)node * 3 + 2] * w0;
    float b0a = 0.f, b1a = 0.f, b2a = 0.f;
    int e = row_ptr[node];
    int e1 = row_ptr[node + 1];
    for (; e + 2 <= e1; e += 2) {
        int2 swa = csr[e], swb = csr[e + 1];
        float wa = __int_as_float(swa.y), wb = __int_as_float(swb.y);
        const float* ua = &u[(size_t)swa.x * 3];
        const float* ub = &u[(size_t)swb.x * 3];
        s0 = fmaf(ua[0], wa, s0);
        s1 = fmaf(ua[1], wa, s1);
        s2 = fmaf(ua[2], wa, s2);
        b0a = fmaf(ub[0], wb, b0a);
        b1a = fmaf(ub[1], wb, b1a);
        b2a = fmaf(ub[2], wb, b2a);
    }
    for (; e < e1; ++e) {
        int2 sw = csr[e];
        float w = __int_as_float(sw.y);
        const float* us = &u[(size_t)sw.x * 3];
        s0 = fmaf(us[0], w, s0);
        s1 = fmaf(us[1], w, s1);
        s2 = fmaf(us[2], w, s2);
    }
    out[(size_t)node * 3 + 0] = tanhf(s0 + b0a + bout[0]) * 0.5f;
    out[(size_t)node * 3 + 1] = tanhf(s1 + b1a + bout[1]) * 0.5f;
    out[(size_t)node * 3 + 2] = tanhf(s2 + b2a + bout[2]) * 0.5f;
}

// ---------------- launch ----------------

extern "C" void kernel_launch(void* const* d_in, const int* in_sizes, int n_in,
                              void* d_out, int out_size, void* d_ws, size_t ws_size,
                              hipStream_t stream) {
    const float* x        = (const float*)d_in[0];
    const int*   ei       = (const int*)d_in[1];   // int32: [2, NE] row-major
    const float* W0       = (const float*)d_in[2];
    const float* b0       = (const float*)d_in[3];
    const float* Wh       = (const float*)d_in[4];
    const float* bh       = (const float*)d_in[5];
    const float* Wout     = (const float*)d_in[6];
    const float* bout     = (const float*)d_in[7];
    float* out            = (float*)d_out;

    char* ws = (char*)d_ws;
    float*  bufA   = (float*)(ws + 0);              // NN*128 fp32 = 15,360,000 B
    __half* bufB16 = (__half*)(ws + 15360000);      // NN*128 fp16 = 7,680,000 B
    float*  dinv   = (float*)(ws + 23040000);       // NN floats
    int*    cnt    = (int*)  (ws + 23160000);       // NN ints
    int*    row_ptr= (int*)  (ws + 23280000);       // NN+1 ints (padded)
    int*    cursor = (int*)  (ws + 23400064);       // NN ints
    int2*   csr    = (int2*) (ws + 23520064);       // NE int2 = 3,840,000 B

    // scan temporaries: borrow bufA space (unused until after CSR build)
    int* bsum = (int*)bufA;        // NB ints
    int* boff = bsum + 256;        // NB ints

    hipMemsetAsync(cnt, 0, NN * sizeof(int), stream);
    k_count<<<(NE + 255) / 256, 256, 0, stream>>>(ei, cnt);
    k_scan1<<<NB, 256, 0, stream>>>(cnt, bsum, dinv);
    k_scan2<<<1, 128, 0, stream>>>(bsum, boff);
    k_scan3<<<NB, 256, 0, stream>>>(cnt, boff, row_ptr, cursor);
    k_fill<<<(NE + 255) / 256, 256, 0, stream>>>(ei, dinv, cursor, csr);

    // layer 0: h1 = fp16(lrelu((A_hat x) @ W0 + b0))   (x fp32, 64ch gather)
    k_agg<64><<<NN / 16, 256, 0, stream>>>(x, row_ptr, csr, dinv, bufA);
    k_gemm<64><<<(NN + 31) / 32, 256, 0, stream>>>(bufA, W0, b0, bufB16);

    // hidden layers: h = fp16(lrelu((A_hat h16) @ Wh[i] + bh[i]))
    for (int i = 0; i < 6; i++) {
        k_agg16<<<NN / 8, 256, 0, stream>>>(bufB16, row_ptr, csr, dinv, bufA);
        k_gemm<128><<<(NN + 31) / 32, 256, 0, stream>>>(bufA, Wh + (size_t)i * 128 * 128,
                                                        bh + (size_t)i * 128, bufB16);
    }

    // final: out = tanh(A_hat (h16 @ Wout) + bout) * 0.5   (GEMM-first: 3ch gather)
    k_out_gemm<<<(NN + 7) / 8, 256, 0, stream>>>(bufB16, Wout, bufA /* u: NN x 3 */);
    k_agg_out<<<(NN + 255) / 256, 256, 0, stream>>>(bufA, row_ptr, csr, dinv, bout, out);
}

// Round 8
// 440.875 us; speedup vs baseline: 1.3771x; 1.1260x over previous
//
#include <hip/hip_runtime.h>
#include <hip/hip_fp16.h>
#include <math.h>

#define NN 30000
#define NE 480000
#define NB 118   // ceil(NN/256)
#define SCALE 512.0f
#define INVSCALE (1.0f / 512.0f)

typedef _Float16 half8 __attribute__((ext_vector_type(8)));
typedef float floatx4 __attribute__((ext_vector_type(4)));

__device__ __forceinline__ float lrelu(float v) { return v > 0.0f ? v : v * 0.02f; }

__device__ __forceinline__ float4 fma4(float4 v, float w, float4 a) {
    a.x = fmaf(v.x, w, a.x);
    a.y = fmaf(v.y, w, a.y);
    a.z = fmaf(v.z, w, a.z);
    a.w = fmaf(v.w, w, a.w);
    return a;
}

__device__ __forceinline__ float4 loadh4(const __half* p) {
    uint2 raw = *(const uint2*)p;
    __half2 h0 = *(__half2*)&raw.x;
    __half2 h1 = *(__half2*)&raw.y;
    float2 f0 = __half22float2(h0);
    float2 f1 = __half22float2(h1);
    return make_float4(f0.x, f0.y, f1.x, f1.y);
}

__device__ __forceinline__ void storeh4(__half* p, float4 v) {
    __half2 a = __floats2half2_rn(v.x, v.y);
    __half2 b = __floats2half2_rn(v.z, v.w);
    uint2 pk;
    pk.x = *(unsigned int*)&a;
    pk.y = *(unsigned int*)&b;
    *(uint2*)p = pk;
}

// ---------------- CSR build ----------------

__global__ void k_count(const int* __restrict__ ei, int* __restrict__ cnt) {
    int e = blockIdx.x * 256 + threadIdx.x;
    if (e < NE) atomicAdd(&cnt[ei[NE + e]], 1);
}

__global__ void k_scan1(const int* __restrict__ cnt, int* __restrict__ bsum,
                        float* __restrict__ dinv) {
    __shared__ int sd[256];
    int tid = threadIdx.x;
    int i = blockIdx.x * 256 + tid;
    int v = (i < NN) ? cnt[i] : 0;
    if (i < NN) dinv[i] = 1.0f / sqrtf((float)(v + 1));  // +1 self loop
    sd[tid] = v;
    __syncthreads();
    for (int off = 128; off > 0; off >>= 1) {
        if (tid < off) sd[tid] += sd[tid + off];
        __syncthreads();
    }
    if (tid == 0) bsum[blockIdx.x] = sd[0];
}

__global__ void k_scan2(const int* __restrict__ bsum, int* __restrict__ boff) {
    __shared__ int sd[128];
    int tid = threadIdx.x;
    int v = (tid < NB) ? bsum[tid] : 0;
    sd[tid] = v;
    __syncthreads();
    for (int off = 1; off < 128; off <<= 1) {
        int t = (tid >= off) ? sd[tid - off] : 0;
        __syncthreads();
        sd[tid] += t;
        __syncthreads();
    }
    if (tid < NB) boff[tid] = sd[tid] - v;  // exclusive
}

__global__ void k_scan3(const int* __restrict__ cnt, const int* __restrict__ boff,
                        int* __restrict__ row_ptr, int* __restrict__ cursor) {
    __shared__ int sd[256];
    int tid = threadIdx.x;
    int i = blockIdx.x * 256 + tid;
    int v = (i < NN) ? cnt[i] : 0;
    sd[tid] = v;
    __syncthreads();
    for (int off = 1; off < 256; off <<= 1) {
        int t = (tid >= off) ? sd[tid - off] : 0;
        __syncthreads();
        sd[tid] += t;
        __syncthreads();
    }
    if (i < NN) {
        int excl = boff[blockIdx.x] + sd[tid] - v;
        row_ptr[i] = excl;
        cursor[i] = excl;
        if (i == NN - 1) row_ptr[NN] = excl + v;
    }
}

__global__ void k_fill(const int* __restrict__ ei, const float* __restrict__ dinv,
                       int* __restrict__ cursor, int2* __restrict__ csr) {
    int e = blockIdx.x * 256 + threadIdx.x;
    if (e < NE) {
        int s = ei[e];
        int d = ei[NE + e];
        int pos = atomicAdd(&cursor[d], 1);
        float w = dinv[s] * dinv[d];
        csr[pos] = make_int2(s, __float_as_int(w));
    }
}

// ---------------- weight convert: W -> fp16 transposed [n][k]; biases scaled ----------------
// W0 scaled by SCALE (injects h' = SCALE*h); all biases scaled by SCALE.

__global__ void k_convw(const float* __restrict__ W0, const float* __restrict__ Wh,
                        const float* __restrict__ b0, const float* __restrict__ bh,
                        __half* __restrict__ W0t, __half* __restrict__ Wht,
                        float* __restrict__ bs) {
    int i = blockIdx.x * 256 + threadIdx.x;
    if (i < 8192) {                       // W0 [64,128] -> W0t [128][64], *SCALE
        int k = i >> 7, n = i & 127;
        W0t[n * 64 + k] = __float2half(W0[i] * SCALE);
    } else if (i < 8192 + 98304) {        // Wh [6][128,128] -> Wht [6][128n][128k]
        int j = i - 8192;
        int l = j >> 14;
        int r = j & 16383;
        int k = r >> 7, n = r & 127;
        Wht[l * 16384 + n * 128 + k] = __float2half(Wh[j]);
    } else if (i < 8192 + 98304 + 896) {  // biases: [b0 | bh0..bh5] * SCALE
        int j = i - 8192 - 98304;
        bs[j] = (j < 128 ? b0[j] : bh[j - 128]) * SCALE;
    }
}

// ---------------- layer-0 aggregation: fp32 x in, fp16 out (64 ch) ----------------

__launch_bounds__(256)
__global__ void k_agg0(const float* __restrict__ h, const int* __restrict__ row_ptr,
                       const int2* __restrict__ csr, const float* __restrict__ dinv,
                       __half* __restrict__ out) {
    int node = blockIdx.x * 16 + (threadIdx.x >> 4);   // 16 threads/node, C=64
    if (node >= NN) return;
    int c = (threadIdx.x & 15) * 4;
    float di = dinv[node];
    float w0 = di * di;
    float4 hv = *(const float4*)&h[(size_t)node * 64 + c];
    float4 acc[8];
    acc[0] = make_float4(hv.x * w0, hv.y * w0, hv.z * w0, hv.w * w0);
    #pragma unroll
    for (int j = 1; j < 8; j++) acc[j] = make_float4(0.f, 0.f, 0.f, 0.f);

    int e = row_ptr[node];
    int e1 = row_ptr[node + 1];
    for (; e + 8 <= e1; e += 8) {
        int2 sw[8];
        #pragma unroll
        for (int j = 0; j < 8; j++) sw[j] = csr[e + j];
        float4 v[8];
        #pragma unroll
        for (int j = 0; j < 8; j++) v[j] = *(const float4*)&h[(size_t)sw[j].x * 64 + c];
        #pragma unroll
        for (int j = 0; j < 8; j++) acc[j] = fma4(v[j], __int_as_float(sw[j].y), acc[j]);
    }
    for (; e < e1; ++e) {
        int2 sw = csr[e];
        float4 v = *(const float4*)&h[(size_t)sw.x * 64 + c];
        acc[0] = fma4(v, __int_as_float(sw.y), acc[0]);
    }
    #pragma unroll
    for (int j = 1; j < 8; j++) {
        acc[0].x += acc[j].x;
        acc[0].y += acc[j].y;
        acc[0].z += acc[j].z;
        acc[0].w += acc[j].w;
    }
    storeh4(&out[(size_t)node * 64 + c], acc[0]);
}

// ---------------- hidden aggregation: fp16 in, fp16 out (128 ch), fp32 accumulate ----------------

__launch_bounds__(256)
__global__ void k_agg16(const __half* __restrict__ h, const int* __restrict__ row_ptr,
                        const int2* __restrict__ csr, const float* __restrict__ dinv,
                        __half* __restrict__ out) {
    int node = blockIdx.x * 8 + (threadIdx.x >> 5);   // 32 threads/node, C=128
    if (node >= NN) return;
    int c = (threadIdx.x & 31) * 4;
    float di = dinv[node];
    float w0 = di * di;
    float4 hv = loadh4(&h[(size_t)node * 128 + c]);
    float4 acc[8];
    acc[0] = make_float4(hv.x * w0, hv.y * w0, hv.z * w0, hv.w * w0);
    #pragma unroll
    for (int j = 1; j < 8; j++) acc[j] = make_float4(0.f, 0.f, 0.f, 0.f);

    int e = row_ptr[node];
    int e1 = row_ptr[node + 1];
    for (; e + 8 <= e1; e += 8) {
        int2 sw[8];
        #pragma unroll
        for (int j = 0; j < 8; j++) sw[j] = csr[e + j];
        float4 v[8];
        #pragma unroll
        for (int j = 0; j < 8; j++) v[j] = loadh4(&h[(size_t)sw[j].x * 128 + c]);
        #pragma unroll
        for (int j = 0; j < 8; j++) acc[j] = fma4(v[j], __int_as_float(sw[j].y), acc[j]);
    }
    for (; e < e1; ++e) {
        int2 sw = csr[e];
        float4 v = loadh4(&h[(size_t)sw.x * 128 + c]);
        acc[0] = fma4(v, __int_as_float(sw.y), acc[0]);
    }
    #pragma unroll
    for (int j = 1; j < 8; j++) {
        acc[0].x += acc[j].x;
        acc[0].y += acc[j].y;
        acc[0].z += acc[j].z;
        acc[0].w += acc[j].w;
    }
    storeh4(&out[(size_t)node * 128 + c], acc[0]);
}

// ---------------- MFMA GEMM: out16[N,128] = fp16(lrelu(A16[N,K] @ W + bias)) ----------------
// Wt is fp16 transposed [n][k]. Block = 4 waves x 16 rows = 64 rows, full 128 cols.
// Fragments (verified layouts): A[m=lane&15][k=quad*8+j], B[n=lane&15][k=quad*8+j],
// C/D: col=lane&15, row=quad*4+reg.
// // fp32 VALU k_gemm history: 32-row tile = 24us; 64-row variant spilled (VGPR=256). MFMA replaces both.

template <int K>
__launch_bounds__(256)
__global__ void k_gemm_mfma(const __half* __restrict__ A, const __half* __restrict__ Wt,
                            const float* __restrict__ bias, __half* __restrict__ out16) {
    constexpr int KS = K / 32;            // k-steps per mfma chain
    int tid = threadIdx.x;
    int wave = tid >> 6;
    int lane = tid & 63;
    int quad = lane >> 4;
    int ln = lane & 15;
    int rowm = blockIdx.x * 64 + wave * 16 + ln;
    int rowc = rowm < NN ? rowm : NN - 1;

    half8 afrag[KS];
    #pragma unroll
    for (int ks = 0; ks < KS; ks++)
        afrag[ks] = *(const half8*)&A[(size_t)rowc * K + ks * 32 + quad * 8];

    floatx4 acc[8];
    #pragma unroll
    for (int t = 0; t < 8; t++) acc[t] = (floatx4){0.f, 0.f, 0.f, 0.f};

    #pragma unroll
    for (int ks = 0; ks < KS; ks++) {
        #pragma unroll
        for (int t = 0; t < 8; t++) {
            half8 b = *(const half8*)&Wt[(size_t)(t * 16 + ln) * K + ks * 32 + quad * 8];
            acc[t] = __builtin_amdgcn_mfma_f32_16x16x32_f16(afrag[ks], b, acc[t], 0, 0, 0);
        }
    }

    int rowbase = blockIdx.x * 64 + wave * 16 + quad * 4;
    #pragma unroll
    for (int t = 0; t < 8; t++) {
        float b = bias[t * 16 + ln];
        #pragma unroll
        for (int r = 0; r < 4; r++) {
            int row = rowbase + r;
            if (row < NN)
                out16[(size_t)row * 128 + t * 16 + ln] = __float2half(lrelu(acc[t][r] + b));
        }
    }
}

// ---------------- final: u = h16 @ Wout[128,3]  (u is SCALE*true value) ----------------

__launch_bounds__(256)
__global__ void k_out_gemm(const __half* __restrict__ h, const float* __restrict__ Wout,
                           float* __restrict__ u) {
    __shared__ float Ws[128 * 3];
    int tid = threadIdx.x;
    for (int i = tid; i < 384; i += 256) Ws[i] = Wout[i];
    __syncthreads();
    int row = blockIdx.x * 8 + (tid >> 5);
    int lane = tid & 31;
    if (row >= NN) return;
    float4 v = loadh4(&h[(size_t)row * 128 + lane * 4]);
    int k = lane * 4;
    float a0 = v.x * Ws[k * 3 + 0] + v.y * Ws[(k + 1) * 3 + 0] +
               v.z * Ws[(k + 2) * 3 + 0] + v.w * Ws[(k + 3) * 3 + 0];
    float a1 = v.x * Ws[k * 3 + 1] + v.y * Ws[(k + 1) * 3 + 1] +
               v.z * Ws[(k + 2) * 3 + 1] + v.w * Ws[(k + 3) * 3 + 1];
    float a2 = v.x * Ws[k * 3 + 2] + v.y * Ws[(k + 1) * 3 + 2] +
               v.z * Ws[(k + 2) * 3 + 2] + v.w * Ws[(k + 3) * 3 + 2];
    for (int off = 16; off > 0; off >>= 1) {
        a0 += __shfl_down(a0, off, 32);
        a1 += __shfl_down(a1, off, 32);
        a2 += __shfl_down(a2, off, 32);
    }
    if (lane == 0) {
        u[(size_t)row * 3 + 0] = a0;
        u[(size_t)row * 3 + 1] = a1;
        u[(size_t)row * 3 + 2] = a2;
    }
}

// ---------------- final aggregate (3 ch), unscale, + bias, tanh*0.5 ----------------

__global__ void k_agg_out(const float* __restrict__ u, const int* __restrict__ row_ptr,
                          const int2* __restrict__ csr, const float* __restrict__ dinv,
                          const float* __restrict__ bout, float* __restrict__ out) {
    int node = blockIdx.x * 256 + threadIdx.x;
    if (node >= NN) return;
    float di = dinv[node], w0 = di * di;
    float s0 = u[(size_t)node * 3 + 0] * w0;
    float s1 = u[(size_t)node * 3 + 1] * w0;
    float s2 = u[(size_t)node * 3 + 2] * w0;
    float b0a = 0.f, b1a = 0.f, b2a = 0.f;
    int e = row_ptr[node];
    int e1 = row_ptr[node + 1];
    for (; e + 2 <= e1; e += 2) {
        int2 swa = csr[e], swb = csr[e + 1];
        float wa = __int_as_float(swa.y), wb = __int_as_float(swb.y);
        const float* ua = &u[(size_t)swa.x * 3];
        const float* ub = &u[(size_t)swb.x * 3];
        s0 = fmaf(ua[0], wa, s0);
        s1 = fmaf(ua[1], wa, s1);
        s2 = fmaf(ua[2], wa, s2);
        b0a = fmaf(ub[0], wb, b0a);
        b1a = fmaf(ub[1], wb, b1a);
        b2a = fmaf(ub[2], wb, b2a);
    }
    for (; e < e1; ++e) {
        int2 sw = csr[e];
        float w = __int_as_float(sw.y);
        const float* us = &u[(size_t)sw.x * 3];
        s0 = fmaf(us[0], w, s0);
        s1 = fmaf(us[1], w, s1);
        s2 = fmaf(us[2], w, s2);
    }
    out[(size_t)node * 3 + 0] = tanhf((s0 + b0a) * INVSCALE + bout[0]) * 0.5f;
    out[(size_t)node * 3 + 1] = tanhf((s1 + b1a) * INVSCALE + bout[1]) * 0.5f;
    out[(size_t)node * 3 + 2] = tanhf((s2 + b2a) * INVSCALE + bout[2]) * 0.5f;
}

// ---------------- launch ----------------

extern "C" void kernel_launch(void* const* d_in, const int* in_sizes, int n_in,
                              void* d_out, int out_size, void* d_ws, size_t ws_size,
                              hipStream_t stream) {
    const float* x        = (const float*)d_in[0];
    const int*   ei       = (const int*)d_in[1];   // int32: [2, NE] row-major
    const float* W0       = (const float*)d_in[2];
    const float* b0       = (const float*)d_in[3];
    const float* Wh       = (const float*)d_in[4];
    const float* bh       = (const float*)d_in[5];
    const float* Wout     = (const float*)d_in[6];
    const float* bout     = (const float*)d_in[7];
    float* out            = (float*)d_out;

    char* ws = (char*)d_ws;
    float*  bufA   = (float*)(ws + 0);              // NN*128 fp32 = 15,360,000 B (A16 / u scratch)
    __half* bufA16 = (__half*)(ws + 0);             // aliases bufA
    __half* bufB16 = (__half*)(ws + 15360000);      // NN*128 fp16 = 7,680,000 B
    __half* W0t16  = (__half*)(ws + 23040000);      // 64*128 fp16 = 16,384 B
    __half* Wht16  = (__half*)(ws + 23056384);      // 6*128*128 fp16 = 196,608 B
    float*  bs     = (float*)(ws + 23252992);       // 7*128 fp32 scaled biases = 3,584 B
    float*  dinv   = (float*)(ws + 23256576);       // NN floats
    int*    cnt    = (int*)  (ws + 23376576);       // NN ints
    int*    row_ptr= (int*)  (ws + 23496576);       // NN+1 ints (padded)
    int*    cursor = (int*)  (ws + 23616640);       // NN ints
    int2*   csr    = (int2*) (ws + 23736640);       // NE int2 = 3,840,000 B

    // scan temporaries: borrow bufA space (unused until after CSR build)
    int* bsum = (int*)bufA;
    int* boff = bsum + 256;

    hipMemsetAsync(cnt, 0, NN * sizeof(int), stream);
    k_count<<<(NE + 255) / 256, 256, 0, stream>>>(ei, cnt);
    k_scan1<<<NB, 256, 0, stream>>>(cnt, bsum, dinv);
    k_scan2<<<1, 128, 0, stream>>>(bsum, boff);
    k_scan3<<<NB, 256, 0, stream>>>(cnt, boff, row_ptr, cursor);
    k_fill<<<(NE + 255) / 256, 256, 0, stream>>>(ei, dinv, cursor, csr);
    k_convw<<<420, 256, 0, stream>>>(W0, Wh, b0, bh, W0t16, Wht16, bs);

    // layer 0: h1' = fp16(lrelu((A_hat x) @ (S*W0) + S*b0))
    k_agg0<<<NN / 16, 256, 0, stream>>>(x, row_ptr, csr, dinv, bufA16);
    k_gemm_mfma<64><<<(NN + 63) / 64, 256, 0, stream>>>(bufA16, W0t16, bs, bufB16);

    // hidden layers: h' = fp16(lrelu((A_hat h') @ Wh[i] + S*bh[i]))
    for (int i = 0; i < 6; i++) {
        k_agg16<<<NN / 8, 256, 0, stream>>>(bufB16, row_ptr, csr, dinv, bufA16);
        k_gemm_mfma<128><<<(NN + 63) / 64, 256, 0, stream>>>(bufA16, Wht16 + (size_t)i * 16384,
                                                             bs + 128 + (size_t)i * 128, bufB16);
    }

    // final: out = tanh((A_hat (h' @ Wout)) / S + bout) * 0.5
    k_out_gemm<<<(NN + 7) / 8, 256, 0, stream>>>(bufB16, Wout, bufA /* u' : NN x 3 */);
    k_agg_out<<<(NN + 255) / 256, 256, 0, stream>>>(bufA, row_ptr, csr, dinv, bout, out);
}

// Round 9
// 368.487 us; speedup vs baseline: 1.6477x; 1.1964x over previous
//
#include <hip/hip_runtime.h>
#include <hip/hip_fp16.h>
#include <math.h>

#define NN 30000
#define NE 480000
#define NB 118   // ceil(NN/256)
#define SCALE 512.0f
#define INVSCALE (1.0f / 512.0f)

typedef _Float16 half8 __attribute__((ext_vector_type(8)));
typedef float floatx4 __attribute__((ext_vector_type(4)));

__device__ __forceinline__ float lrelu(float v) { return v > 0.0f ? v : v * 0.02f; }

__device__ __forceinline__ float4 fma4(float4 v, float w, float4 a) {
    a.x = fmaf(v.x, w, a.x);
    a.y = fmaf(v.y, w, a.y);
    a.z = fmaf(v.z, w, a.z);
    a.w = fmaf(v.w, w, a.w);
    return a;
}

__device__ __forceinline__ float4 loadh4(const __half* p) {
    uint2 raw = *(const uint2*)p;
    __half2 h0 = *(__half2*)&raw.x;
    __half2 h1 = *(__half2*)&raw.y;
    float2 f0 = __half22float2(h0);
    float2 f1 = __half22float2(h1);
    return make_float4(f0.x, f0.y, f1.x, f1.y);
}

// ---------------- CSR build (+ fused weight convert) ----------------

__global__ void k_count(const int* __restrict__ ei, int* __restrict__ cnt,
                        const float* __restrict__ W0, const float* __restrict__ Wh,
                        const float* __restrict__ b0, const float* __restrict__ bh,
                        __half* __restrict__ W0t, __half* __restrict__ Wht,
                        float* __restrict__ bs) {
    int g = blockIdx.x * 256 + threadIdx.x;
    if (g < NE) atomicAdd(&cnt[ei[NE + g]], 1);
    // fused convw (107392 items << NE threads)
    if (g < 8192) {                       // W0 [64,128] -> W0t [128n][64k], *SCALE
        int k = g >> 7, n = g & 127;
        W0t[n * 64 + k] = __float2half(W0[g] * SCALE);
    } else if (g < 8192 + 98304) {        // Wh [6][128,128] -> Wht [6][128n][128k]
        int j = g - 8192;
        int l = j >> 14;
        int r = j & 16383;
        int k = r >> 7, n = r & 127;
        Wht[l * 16384 + n * 128 + k] = __float2half(Wh[j]);
    } else if (g < 8192 + 98304 + 896) {  // biases: [b0 | bh0..bh5] * SCALE
        int j = g - 8192 - 98304;
        bs[j] = (j < 128 ? b0[j] : bh[j - 128]) * SCALE;
    }
}

__global__ void k_scan1(const int* __restrict__ cnt, int* __restrict__ bsum,
                        float* __restrict__ dinv) {
    __shared__ int sd[256];
    int tid = threadIdx.x;
    int i = blockIdx.x * 256 + tid;
    int v = (i < NN) ? cnt[i] : 0;
    if (i < NN) dinv[i] = 1.0f / sqrtf((float)(v + 1));  // +1 self loop
    sd[tid] = v;
    __syncthreads();
    for (int off = 128; off > 0; off >>= 1) {
        if (tid < off) sd[tid] += sd[tid + off];
        __syncthreads();
    }
    if (tid == 0) bsum[blockIdx.x] = sd[0];
}

// merged scan2+scan3: each block reduces its own offset from bsum, then local scan
__global__ void k_scan3(const int* __restrict__ cnt, const int* __restrict__ bsum,
                        int* __restrict__ row_ptr, int* __restrict__ cursor) {
    __shared__ int sd[256];
    __shared__ int offs[128];
    int tid = threadIdx.x;
    if (tid < 128) offs[tid] = (tid < blockIdx.x) ? bsum[tid] : 0;  // blockIdx < NB <= 128
    __syncthreads();
    for (int o = 64; o > 0; o >>= 1) {
        if (tid < o) offs[tid] += offs[tid + o];
        __syncthreads();
    }
    int i = blockIdx.x * 256 + tid;
    int v = (i < NN) ? cnt[i] : 0;
    sd[tid] = v;
    __syncthreads();
    for (int off = 1; off < 256; off <<= 1) {
        int t = (tid >= off) ? sd[tid - off] : 0;
        __syncthreads();
        sd[tid] += t;
        __syncthreads();
    }
    if (i < NN) {
        int excl = offs[0] + sd[tid] - v;
        row_ptr[i] = excl;
        cursor[i] = excl;
        if (i == NN - 1) row_ptr[NN] = excl + v;
    }
}

__global__ void k_fill(const int* __restrict__ ei, const float* __restrict__ dinv,
                       int* __restrict__ cursor, int2* __restrict__ csr) {
    int e = blockIdx.x * 256 + threadIdx.x;
    if (e < NE) {
        int s = ei[e];
        int d = ei[NE + e];
        int pos = atomicAdd(&cursor[d], 1);
        float w = dinv[s] * dinv[d];
        csr[pos] = make_int2(s, __float_as_int(w));
    }
}

// ================= fused layer kernels: agg -> LDS (A-fragment order) -> MFMA =================
// Block = 16 nodes (= one 16-row MFMA tile), 512 threads (8 waves).
// Agg phase: 32 thr/node (same wave structure/occupancy as the standalone agg: 15000 waves).
// LDS layout hsF[ks][quad][row16][8] so MFMA-side ds_read_b128 is 2-way aliased (free);
// the single fragment-store per thread is 16-way conflicted but happens once per layer.
// NN % 16 == 0 and NE % 256 == 0: no tail guards needed.

// ---- layer 0: x fp32 [NN,64] -> out16 = fp16(lrelu((A_hat x) @ W0t + bias)) ----
__launch_bounds__(512)
__global__ void k_layer0(const float* __restrict__ x, const int* __restrict__ row_ptr,
                         const int2* __restrict__ csr, const float* __restrict__ dinv,
                         const __half* __restrict__ Wt, const float* __restrict__ bias,
                         __half* __restrict__ out16) {
    __shared__ _Float16 hsF[2 * 4 * 16 * 8];  // [ks][quad][row][8] = 2 KB
    int tid = threadIdx.x;
    int node0 = blockIdx.x * 16;
    {
        int nl = tid >> 5;               // local node 0..15
        int node = node0 + nl;
        int c = (tid & 31) * 2;          // 2 fp32 channels per lane
        float di = dinv[node];
        float w0 = di * di;
        float2 hv = *(const float2*)&x[(size_t)node * 64 + c];
        float2 acc[8];
        acc[0] = make_float2(hv.x * w0, hv.y * w0);
        #pragma unroll
        for (int j = 1; j < 8; j++) acc[j] = make_float2(0.f, 0.f);
        int e = row_ptr[node];
        int e1 = row_ptr[node + 1];
        for (; e + 8 <= e1; e += 8) {
            int2 sw[8];
            #pragma unroll
            for (int j = 0; j < 8; j++) sw[j] = csr[e + j];
            float2 v[8];
            #pragma unroll
            for (int j = 0; j < 8; j++) v[j] = *(const float2*)&x[(size_t)sw[j].x * 64 + c];
            #pragma unroll
            for (int j = 0; j < 8; j++) {
                float w = __int_as_float(sw[j].y);
                acc[j].x = fmaf(v[j].x, w, acc[j].x);
                acc[j].y = fmaf(v[j].y, w, acc[j].y);
            }
        }
        for (; e < e1; ++e) {
            int2 sw = csr[e];
            float2 v = *(const float2*)&x[(size_t)sw.x * 64 + c];
            float w = __int_as_float(sw.y);
            acc[0].x = fmaf(v.x, w, acc[0].x);
            acc[0].y = fmaf(v.y, w, acc[0].y);
        }
        #pragma unroll
        for (int j = 1; j < 8; j++) { acc[0].x += acc[j].x; acc[0].y += acc[j].y; }
        int ks = c >> 5, quad = (c >> 3) & 3, jj = c & 7;
        __half2 p = __floats2half2_rn(acc[0].x, acc[0].y);
        *(__half2*)&hsF[((ks * 4 + quad) * 16 + nl) * 8 + jj] = p;
    }
    __syncthreads();
    int wave = tid >> 6, lane = tid & 63, quad = lane >> 4, ln = lane & 15;
    half8 afrag[2];
    #pragma unroll
    for (int ks = 0; ks < 2; ks++)
        afrag[ks] = *(const half8*)&hsF[((ks * 4 + quad) * 16 + ln) * 8];
    floatx4 acc = (floatx4){0.f, 0.f, 0.f, 0.f};
    #pragma unroll
    for (int ks = 0; ks < 2; ks++) {
        half8 b = *(const half8*)&Wt[(size_t)(wave * 16 + ln) * 64 + ks * 32 + quad * 8];
        acc = __builtin_amdgcn_mfma_f32_16x16x32_f16(afrag[ks], b, acc, 0, 0, 0);
    }
    int col = wave * 16 + ln;
    float bb = bias[col];
    #pragma unroll
    for (int r = 0; r < 4; r++) {
        int row = node0 + quad * 4 + r;
        out16[(size_t)row * 128 + col] = __float2half(lrelu(acc[r] + bb));
    }
}

// ---- hidden layer: h fp16 [NN,128] -> out16 = fp16(lrelu((A_hat h) @ Wt + bias)) ----
__launch_bounds__(512)
__global__ void k_layer_h(const __half* __restrict__ h, const int* __restrict__ row_ptr,
                          const int2* __restrict__ csr, const float* __restrict__ dinv,
                          const __half* __restrict__ Wt, const float* __restrict__ bias,
                          __half* __restrict__ out16) {
    __shared__ _Float16 hsF[4 * 4 * 16 * 8];  // [ks][quad][row][8] = 4 KB
    int tid = threadIdx.x;
    int node0 = blockIdx.x * 16;
    {
        int nl = tid >> 5;               // local node 0..15
        int node = node0 + nl;
        int c = (tid & 31) * 4;          // 4 fp16 channels per lane
        float di = dinv[node];
        float w0 = di * di;
        float4 hv = loadh4(&h[(size_t)node * 128 + c]);
        float4 acc[8];
        acc[0] = make_float4(hv.x * w0, hv.y * w0, hv.z * w0, hv.w * w0);
        #pragma unroll
        for (int j = 1; j < 8; j++) acc[j] = make_float4(0.f, 0.f, 0.f, 0.f);
        int e = row_ptr[node];
        int e1 = row_ptr[node + 1];
        for (; e + 8 <= e1; e += 8) {
            int2 sw[8];
            #pragma unroll
            for (int j = 0; j < 8; j++) sw[j] = csr[e + j];
            float4 v[8];
            #pragma unroll
            for (int j = 0; j < 8; j++) v[j] = loadh4(&h[(size_t)sw[j].x * 128 + c]);
            #pragma unroll
            for (int j = 0; j < 8; j++) acc[j] = fma4(v[j], __int_as_float(sw[j].y), acc[j]);
        }
        for (; e < e1; ++e) {
            int2 sw = csr[e];
            float4 v = loadh4(&h[(size_t)sw.x * 128 + c]);
            acc[0] = fma4(v, __int_as_float(sw.y), acc[0]);
        }
        #pragma unroll
        for (int j = 1; j < 8; j++) {
            acc[0].x += acc[j].x;
            acc[0].y += acc[j].y;
            acc[0].z += acc[j].z;
            acc[0].w += acc[j].w;
        }
        int ks = c >> 5, quad = (c >> 3) & 3, jj = c & 7;
        __half2 p0 = __floats2half2_rn(acc[0].x, acc[0].y);
        __half2 p1 = __floats2half2_rn(acc[0].z, acc[0].w);
        uint2 pk;
        pk.x = *(unsigned int*)&p0;
        pk.y = *(unsigned int*)&p1;
        *(uint2*)&hsF[((ks * 4 + quad) * 16 + nl) * 8 + jj] = pk;
    }
    __syncthreads();
    int wave = tid >> 6, lane = tid & 63, quad = lane >> 4, ln = lane & 15;
    half8 afrag[4];
    #pragma unroll
    for (int ks = 0; ks < 4; ks++)
        afrag[ks] = *(const half8*)&hsF[((ks * 4 + quad) * 16 + ln) * 8];
    floatx4 acc = (floatx4){0.f, 0.f, 0.f, 0.f};
    #pragma unroll
    for (int ks = 0; ks < 4; ks++) {
        half8 b = *(const half8*)&Wt[(size_t)(wave * 16 + ln) * 128 + ks * 32 + quad * 8];
        acc = __builtin_amdgcn_mfma_f32_16x16x32_f16(afrag[ks], b, acc, 0, 0, 0);
    }
    int col = wave * 16 + ln;
    float bb = bias[col];
    #pragma unroll
    for (int r = 0; r < 4; r++) {
        int row = node0 + quad * 4 + r;
        out16[(size_t)row * 128 + col] = __float2half(lrelu(acc[r] + bb));
    }
}

// ---------------- final: u = h16 @ Wout[128,3]  (u is SCALE*true value) ----------------

__launch_bounds__(256)
__global__ void k_out_gemm(const __half* __restrict__ h, const float* __restrict__ Wout,
                           float* __restrict__ u) {
    __shared__ float Ws[128 * 3];
    int tid = threadIdx.x;
    for (int i = tid; i < 384; i += 256) Ws[i] = Wout[i];
    __syncthreads();
    int row = blockIdx.x * 8 + (tid >> 5);
    int lane = tid & 31;
    if (row >= NN) return;
    float4 v = loadh4(&h[(size_t)row * 128 + lane * 4]);
    int k = lane * 4;
    float a0 = v.x * Ws[k * 3 + 0] + v.y * Ws[(k + 1) * 3 + 0] +
               v.z * Ws[(k + 2) * 3 + 0] + v.w * Ws[(k + 3) * 3 + 0];
    float a1 = v.x * Ws[k * 3 + 1] + v.y * Ws[(k + 1) * 3 + 1] +
               v.z * Ws[(k + 2) * 3 + 1] + v.w * Ws[(k + 3) * 3 + 1];
    float a2 = v.x * Ws[k * 3 + 2] + v.y * Ws[(k + 1) * 3 + 2] +
               v.z * Ws[(k + 2) * 3 + 2] + v.w * Ws[(k + 3) * 3 + 2];
    for (int off = 16; off > 0; off >>= 1) {
        a0 += __shfl_down(a0, off, 32);
        a1 += __shfl_down(a1, off, 32);
        a2 += __shfl_down(a2, off, 32);
    }
    if (lane == 0) {
        u[(size_t)row * 3 + 0] = a0;
        u[(size_t)row * 3 + 1] = a1;
        u[(size_t)row * 3 + 2] = a2;
    }
}

// ---------------- final aggregate (3 ch), unscale, + bias, tanh*0.5 ----------------

__global__ void k_agg_out(const float* __restrict__ u, const int* __restrict__ row_ptr,
                          const int2* __restrict__ csr, const float* __restrict__ dinv,
                          const float* __restrict__ bout, float* __restrict__ out) {
    int node = blockIdx.x * 256 + threadIdx.x;
    if (node >= NN) return;
    float di = dinv[node], w0 = di * di;
    float s0 = u[(size_t)node * 3 + 0] * w0;
    float s1 = u[(size_t)node * 3 + 1] * w0;
    float s2 = u[(size_t)node * 3 + 2] * w0;
    float b0a = 0.f, b1a = 0.f, b2a = 0.f;
    int e = row_ptr[node];
    int e1 = row_ptr[node + 1];
    for (; e + 2 <= e1; e += 2) {
        int2 swa = csr[e], swb = csr[e + 1];
        float wa = __int_as_float(swa.y), wb = __int_as_float(swb.y);
        const float* ua = &u[(size_t)swa.x * 3];
        const float* ub = &u[(size_t)swb.x * 3];
        s0 = fmaf(ua[0], wa, s0);
        s1 = fmaf(ua[1], wa, s1);
        s2 = fmaf(ua[2], wa, s2);
        b0a = fmaf(ub[0], wb, b0a);
        b1a = fmaf(ub[1], wb, b1a);
        b2a = fmaf(ub[2], wb, b2a);
    }
    for (; e < e1; ++e) {
        int2 sw = csr[e];
        float w = __int_as_float(sw.y);
        const float* us = &u[(size_t)sw.x * 3];
        s0 = fmaf(us[0], w, s0);
        s1 = fmaf(us[1], w, s1);
        s2 = fmaf(us[2], w, s2);
    }
    out[(size_t)node * 3 + 0] = tanhf((s0 + b0a) * INVSCALE + bout[0]) * 0.5f;
    out[(size_t)node * 3 + 1] = tanhf((s1 + b1a) * INVSCALE + bout[1]) * 0.5f;
    out[(size_t)node * 3 + 2] = tanhf((s2 + b2a) * INVSCALE + bout[2]) * 0.5f;
}

// ---------------- launch ----------------

extern "C" void kernel_launch(void* const* d_in, const int* in_sizes, int n_in,
                              void* d_out, int out_size, void* d_ws, size_t ws_size,
                              hipStream_t stream) {
    const float* x        = (const float*)d_in[0];
    const int*   ei       = (const int*)d_in[1];   // int32: [2, NE] row-major
    const float* W0       = (const float*)d_in[2];
    const float* b0       = (const float*)d_in[3];
    const float* Wh       = (const float*)d_in[4];
    const float* bh       = (const float*)d_in[5];
    const float* Wout     = (const float*)d_in[6];
    const float* bout     = (const float*)d_in[7];
    float* out            = (float*)d_out;

    char* ws = (char*)d_ws;
    float*  bufA   = (float*)(ws + 0);              // u (NN x 3 fp32) + scan temps
    __half* bufB16 = (__half*)(ws + 15360000);      // NN*128 fp16 = 7,680,000 B
    __half* bufC16 = (__half*)(ws + 23040000);      // NN*128 fp16 = 7,680,000 B
    __half* W0t16  = (__half*)(ws + 30720000);      // 128*64 fp16
    __half* Wht16  = (__half*)(ws + 30736384);      // 6*128*128 fp16
    float*  bs     = (float*)(ws + 30932992);       // 7*128 fp32 scaled biases
    float*  dinv   = (float*)(ws + 30936576);       // NN floats
    int*    cnt    = (int*)  (ws + 31056576);       // NN ints
    int*    row_ptr= (int*)  (ws + 31176576);       // NN+1 ints (padded)
    int*    cursor = (int*)  (ws + 31296640);       // NN ints
    int2*   csr    = (int2*) (ws + 31416640);       // NE int2 = 3,840,000 B

    // scan temporaries: borrow bufA space (unused until final stage)
    int* bsum = (int*)bufA;   // NB ints

    hipMemsetAsync(cnt, 0, NN * sizeof(int), stream);
    k_count<<<(NE + 255) / 256, 256, 0, stream>>>(ei, cnt, W0, Wh, b0, bh, W0t16, Wht16, bs);
    k_scan1<<<NB, 256, 0, stream>>>(cnt, bsum, dinv);
    k_scan3<<<NB, 256, 0, stream>>>(cnt, bsum, row_ptr, cursor);
    k_fill<<<(NE + 255) / 256, 256, 0, stream>>>(ei, dinv, cursor, csr);

    // layer 0 (fused agg+MFMA): h1' = fp16(lrelu((A_hat x) @ (S*W0) + S*b0))
    k_layer0<<<NN / 16, 512, 0, stream>>>(x, row_ptr, csr, dinv, W0t16, bs, bufB16);

    // hidden layers (fused): ping-pong bufB16 <-> bufC16; 6 layers ends back in bufB16
    __half* hin = bufB16;
    __half* hout = bufC16;
    for (int i = 0; i < 6; i++) {
        k_layer_h<<<NN / 16, 512, 0, stream>>>(hin, row_ptr, csr, dinv,
                                               Wht16 + (size_t)i * 16384,
                                               bs + 128 + (size_t)i * 128, hout);
        __half* t = hin; hin = hout; hout = t;
    }
    // hin now holds h7' (bufB16)

    // final: out = tanh((A_hat (h' @ Wout)) / S + bout) * 0.5
    k_out_gemm<<<(NN + 7) / 8, 256, 0, stream>>>(hin, Wout, bufA /* u' : NN x 3 */);
    k_agg_out<<<(NN + 255) / 256, 256, 0, stream>>>(bufA, row_ptr, csr, dinv, bout, out);
}

// Round 10
// 323.174 us; speedup vs baseline: 1.8787x; 1.1402x over previous
//
#include <hip/hip_runtime.h>
#include <hip/hip_fp16.h>
#include <math.h>

#define NN 30000
#define NE 480000
#define NB 118   // ceil(NN/256)
#define SCALE 512.0f
#define INVSCALE (1.0f / 512.0f)

typedef _Float16 half8 __attribute__((ext_vector_type(8)));
typedef float floatx4 __attribute__((ext_vector_type(4)));

__device__ __forceinline__ float lrelu(float v) { return v > 0.0f ? v : v * 0.02f; }

__device__ __forceinline__ float4 fma4(float4 v, float w, float4 a) {
    a.x = fmaf(v.x, w, a.x);
    a.y = fmaf(v.y, w, a.y);
    a.z = fmaf(v.z, w, a.z);
    a.w = fmaf(v.w, w, a.w);
    return a;
}

__device__ __forceinline__ float4 loadh4(const __half* p) {
    uint2 raw = *(const uint2*)p;
    __half2 h0 = *(__half2*)&raw.x;
    __half2 h1 = *(__half2*)&raw.y;
    float2 f0 = __half22float2(h0);
    float2 f1 = __half22float2(h1);
    return make_float4(f0.x, f0.y, f1.x, f1.y);
}

// load 8 halfs (16B) -> two float4
__device__ __forceinline__ void loadh8(const __half* p, float4* lo, float4* hi) {
    uint4 raw = *(const uint4*)p;
    float2 f0 = __half22float2(*(__half2*)&raw.x);
    float2 f1 = __half22float2(*(__half2*)&raw.y);
    float2 f2 = __half22float2(*(__half2*)&raw.z);
    float2 f3 = __half22float2(*(__half2*)&raw.w);
    *lo = make_float4(f0.x, f0.y, f1.x, f1.y);
    *hi = make_float4(f2.x, f2.y, f3.x, f3.y);
}

// ---------------- CSR build (+ fused weight convert + x->fp16) ----------------

__global__ void k_count(const int* __restrict__ ei, int* __restrict__ cnt,
                        const float* __restrict__ W0, const float* __restrict__ Wh,
                        const float* __restrict__ b0, const float* __restrict__ bh,
                        const float* __restrict__ x,
                        __half* __restrict__ W0t, __half* __restrict__ Wht,
                        float* __restrict__ bs, __half* __restrict__ x16) {
    int g = blockIdx.x * 256 + threadIdx.x;
    if (g < NE) atomicAdd(&cnt[ei[NE + g]], 1);
    // x -> fp16: 1.92M elements, 4 per thread (exactly covers 480000 threads)
    {
        float4 v = *(const float4*)&x[(size_t)g * 4];
        __half2 a = __floats2half2_rn(v.x, v.y);
        __half2 b = __floats2half2_rn(v.z, v.w);
        uint2 pk;
        pk.x = *(unsigned int*)&a;
        pk.y = *(unsigned int*)&b;
        *(uint2*)&x16[(size_t)g * 4] = pk;
    }
    // fused weight convert (107392 items << NE threads)
    if (g < 8192) {                       // W0 [64,128] -> W0t [128n][64k], *SCALE
        int k = g >> 7, n = g & 127;
        W0t[n * 64 + k] = __float2half(W0[g] * SCALE);
    } else if (g < 8192 + 98304) {        // Wh [6][128,128] -> Wht [6][128n][128k]
        int j = g - 8192;
        int l = j >> 14;
        int r = j & 16383;
        int k = r >> 7, n = r & 127;
        Wht[l * 16384 + n * 128 + k] = __float2half(Wh[j]);
    } else if (g < 8192 + 98304 + 896) {  // biases: [b0 | bh0..bh5] * SCALE
        int j = g - 8192 - 98304;
        bs[j] = (j < 128 ? b0[j] : bh[j - 128]) * SCALE;
    }
}

__global__ void k_scan1(const int* __restrict__ cnt, int* __restrict__ bsum,
                        float* __restrict__ dinv) {
    __shared__ int sd[256];
    int tid = threadIdx.x;
    int i = blockIdx.x * 256 + tid;
    int v = (i < NN) ? cnt[i] : 0;
    if (i < NN) dinv[i] = 1.0f / sqrtf((float)(v + 1));  // +1 self loop
    sd[tid] = v;
    __syncthreads();
    for (int off = 128; off > 0; off >>= 1) {
        if (tid < off) sd[tid] += sd[tid + off];
        __syncthreads();
    }
    if (tid == 0) bsum[blockIdx.x] = sd[0];
}

// merged scan2+scan3: each block reduces its own offset from bsum, then local scan
__global__ void k_scan3(const int* __restrict__ cnt, const int* __restrict__ bsum,
                        int* __restrict__ row_ptr, int* __restrict__ cursor) {
    __shared__ int sd[256];
    __shared__ int offs[128];
    int tid = threadIdx.x;
    if (tid < 128) offs[tid] = (tid < blockIdx.x) ? bsum[tid] : 0;  // blockIdx < NB <= 128
    __syncthreads();
    for (int o = 64; o > 0; o >>= 1) {
        if (tid < o) offs[tid] += offs[tid + o];
        __syncthreads();
    }
    int i = blockIdx.x * 256 + tid;
    int v = (i < NN) ? cnt[i] : 0;
    sd[tid] = v;
    __syncthreads();
    for (int off = 1; off < 256; off <<= 1) {
        int t = (tid >= off) ? sd[tid - off] : 0;
        __syncthreads();
        sd[tid] += t;
        __syncthreads();
    }
    if (i < NN) {
        int excl = offs[0] + sd[tid] - v;
        row_ptr[i] = excl;
        cursor[i] = excl;
        if (i == NN - 1) row_ptr[NN] = excl + v;
    }
}

__global__ void k_fill(const int* __restrict__ ei, const float* __restrict__ dinv,
                       int* __restrict__ cursor, int2* __restrict__ csr) {
    int e = blockIdx.x * 256 + threadIdx.x;
    if (e < NE) {
        int s = ei[e];
        int d = ei[NE + e];
        int pos = atomicAdd(&cursor[d], 1);
        float w = dinv[s] * dinv[d];
        csr[pos] = make_int2(s, __float_as_int(w));
    }
}

// ================= fused layer kernels: agg -> LDS (A-fragment order) -> MFMA =================
// Block = 16 nodes (one 16-row MFMA tile), 256 threads (4 waves), 16 thr/node in agg phase.
// Gathers are 16B/lane (hidden) or 8B/lane (layer0, 64ch) -> 1KB / 512B per wave-instruction.
// LDS hsF[ks][quad][row16][8]: MFMA-side ds_read_b128 2-way aliased (free); fragment store
// is one b128 (16-way conflicted, once per node per layer - negligible).
// NN % 16 == 0: no tail guards.

// ---- layer 0: x16 fp16 [NN,64] -> out16 = fp16(lrelu((A_hat x) @ W0t + bias)) ----
__launch_bounds__(256)
__global__ void k_layer0(const __half* __restrict__ x, const int* __restrict__ row_ptr,
                         const int2* __restrict__ csr, const float* __restrict__ dinv,
                         const __half* __restrict__ Wt, const float* __restrict__ bias,
                         __half* __restrict__ out16) {
    __shared__ _Float16 hsF[2 * 4 * 16 * 8];  // 2 KB
    int tid = threadIdx.x;
    int node0 = blockIdx.x * 16;
    {
        int nl = tid >> 4;               // local node 0..15
        int node = node0 + nl;
        int c = (tid & 15) * 4;          // 4 fp16 channels per lane (8B loads)
        float di = dinv[node];
        float w0 = di * di;
        float4 hv = loadh4(&x[(size_t)node * 64 + c]);
        float4 acc[8];
        acc[0] = make_float4(hv.x * w0, hv.y * w0, hv.z * w0, hv.w * w0);
        #pragma unroll
        for (int j = 1; j < 8; j++) acc[j] = make_float4(0.f, 0.f, 0.f, 0.f);
        int e = row_ptr[node];
        int e1 = row_ptr[node + 1];
        for (; e + 8 <= e1; e += 8) {
            int2 sw[8];
            #pragma unroll
            for (int j = 0; j < 8; j++) sw[j] = csr[e + j];
            float4 v[8];
            #pragma unroll
            for (int j = 0; j < 8; j++) v[j] = loadh4(&x[(size_t)sw[j].x * 64 + c]);
            #pragma unroll
            for (int j = 0; j < 8; j++) acc[j] = fma4(v[j], __int_as_float(sw[j].y), acc[j]);
        }
        for (; e < e1; ++e) {
            int2 sw = csr[e];
            float4 v = loadh4(&x[(size_t)sw.x * 64 + c]);
            acc[0] = fma4(v, __int_as_float(sw.y), acc[0]);
        }
        #pragma unroll
        for (int j = 1; j < 8; j++) {
            acc[0].x += acc[j].x;
            acc[0].y += acc[j].y;
            acc[0].z += acc[j].z;
            acc[0].w += acc[j].w;
        }
        int ks = c >> 5, quad = (c >> 3) & 3, jj = c & 7;
        __half2 p0 = __floats2half2_rn(acc[0].x, acc[0].y);
        __half2 p1 = __floats2half2_rn(acc[0].z, acc[0].w);
        uint2 pk;
        pk.x = *(unsigned int*)&p0;
        pk.y = *(unsigned int*)&p1;
        *(uint2*)&hsF[((ks * 4 + quad) * 16 + nl) * 8 + jj] = pk;
    }
    __syncthreads();
    int wave = tid >> 6, lane = tid & 63, quad = lane >> 4, ln = lane & 15;
    half8 afrag[2];
    #pragma unroll
    for (int ks = 0; ks < 2; ks++)
        afrag[ks] = *(const half8*)&hsF[((ks * 4 + quad) * 16 + ln) * 8];
    #pragma unroll
    for (int tc = 0; tc < 2; tc++) {     // 2 col-tiles per wave (8 tiles / 4 waves)
        int tt = wave + tc * 4;
        floatx4 acc = (floatx4){0.f, 0.f, 0.f, 0.f};
        #pragma unroll
        for (int ks = 0; ks < 2; ks++) {
            half8 b = *(const half8*)&Wt[(size_t)(tt * 16 + ln) * 64 + ks * 32 + quad * 8];
            acc = __builtin_amdgcn_mfma_f32_16x16x32_f16(afrag[ks], b, acc, 0, 0, 0);
        }
        int col = tt * 16 + ln;
        float bb = bias[col];
        #pragma unroll
        for (int r = 0; r < 4; r++) {
            int row = node0 + quad * 4 + r;
            out16[(size_t)row * 128 + col] = __float2half(lrelu(acc[r] + bb));
        }
    }
}

// ---- hidden layer: h fp16 [NN,128] -> out16 = fp16(lrelu((A_hat h) @ Wt + bias)) ----
__launch_bounds__(256)
__global__ void k_layer_h(const __half* __restrict__ h, const int* __restrict__ row_ptr,
                          const int2* __restrict__ csr, const float* __restrict__ dinv,
                          const __half* __restrict__ Wt, const float* __restrict__ bias,
                          __half* __restrict__ out16) {
    __shared__ _Float16 hsF[4 * 4 * 16 * 8];  // 4 KB
    int tid = threadIdx.x;
    int node0 = blockIdx.x * 16;
    {
        int nl = tid >> 4;               // local node 0..15
        int node = node0 + nl;
        int c = (tid & 15) * 8;          // 8 fp16 channels per lane (16B b128 loads)
        float di = dinv[node];
        float w0 = di * di;
        float4 hlo, hhi;
        loadh8(&h[(size_t)node * 128 + c], &hlo, &hhi);
        float4 acc[4][2];
        acc[0][0] = make_float4(hlo.x * w0, hlo.y * w0, hlo.z * w0, hlo.w * w0);
        acc[0][1] = make_float4(hhi.x * w0, hhi.y * w0, hhi.z * w0, hhi.w * w0);
        #pragma unroll
        for (int j = 1; j < 4; j++) {
            acc[j][0] = make_float4(0.f, 0.f, 0.f, 0.f);
            acc[j][1] = make_float4(0.f, 0.f, 0.f, 0.f);
        }
        int e = row_ptr[node];
        int e1 = row_ptr[node + 1];
        for (; e + 4 <= e1; e += 4) {
            int2 sw[4];
            #pragma unroll
            for (int j = 0; j < 4; j++) sw[j] = csr[e + j];
            float4 vlo[4], vhi[4];
            #pragma unroll
            for (int j = 0; j < 4; j++)
                loadh8(&h[(size_t)sw[j].x * 128 + c], &vlo[j], &vhi[j]);
            #pragma unroll
            for (int j = 0; j < 4; j++) {
                float w = __int_as_float(sw[j].y);
                acc[j][0] = fma4(vlo[j], w, acc[j][0]);
                acc[j][1] = fma4(vhi[j], w, acc[j][1]);
            }
        }
        for (; e < e1; ++e) {
            int2 sw = csr[e];
            float4 vlo, vhi;
            loadh8(&h[(size_t)sw.x * 128 + c], &vlo, &vhi);
            float w = __int_as_float(sw.y);
            acc[0][0] = fma4(vlo, w, acc[0][0]);
            acc[0][1] = fma4(vhi, w, acc[0][1]);
        }
        #pragma unroll
        for (int j = 1; j < 4; j++) {
            acc[0][0].x += acc[j][0].x; acc[0][0].y += acc[j][0].y;
            acc[0][0].z += acc[j][0].z; acc[0][0].w += acc[j][0].w;
            acc[0][1].x += acc[j][1].x; acc[0][1].y += acc[j][1].y;
            acc[0][1].z += acc[j][1].z; acc[0][1].w += acc[j][1].w;
        }
        int ks = c >> 5, quad = (c >> 3) & 3;   // c%8 == 0: one full fragment group
        __half2 p0 = __floats2half2_rn(acc[0][0].x, acc[0][0].y);
        __half2 p1 = __floats2half2_rn(acc[0][0].z, acc[0][0].w);
        __half2 p2 = __floats2half2_rn(acc[0][1].x, acc[0][1].y);
        __half2 p3 = __floats2half2_rn(acc[0][1].z, acc[0][1].w);
        uint4 pk;
        pk.x = *(unsigned int*)&p0;
        pk.y = *(unsigned int*)&p1;
        pk.z = *(unsigned int*)&p2;
        pk.w = *(unsigned int*)&p3;
        *(uint4*)&hsF[((ks * 4 + quad) * 16 + nl) * 8] = pk;
    }
    __syncthreads();
    int wave = tid >> 6, lane = tid & 63, quad = lane >> 4, ln = lane & 15;
    half8 afrag[4];
    #pragma unroll
    for (int ks = 0; ks < 4; ks++)
        afrag[ks] = *(const half8*)&hsF[((ks * 4 + quad) * 16 + ln) * 8];
    #pragma unroll
    for (int tc = 0; tc < 2; tc++) {     // 2 col-tiles per wave
        int tt = wave + tc * 4;
        floatx4 acc = (floatx4){0.f, 0.f, 0.f, 0.f};
        #pragma unroll
        for (int ks = 0; ks < 4; ks++) {
            half8 b = *(const half8*)&Wt[(size_t)(tt * 16 + ln) * 128 + ks * 32 + quad * 8];
            acc = __builtin_amdgcn_mfma_f32_16x16x32_f16(afrag[ks], b, acc, 0, 0, 0);
        }
        int col = tt * 16 + ln;
        float bb = bias[col];
        #pragma unroll
        for (int r = 0; r < 4; r++) {
            int row = node0 + quad * 4 + r;
            out16[(size_t)row * 128 + col] = __float2half(lrelu(acc[r] + bb));
        }
    }
}

// ---------------- final: u = h16 @ Wout[128,3]  (u is SCALE*true value) ----------------

__launch_bounds__(256)
__global__ void k_out_gemm(const __half* __restrict__ h, const float* __restrict__ Wout,
                           float* __restrict__ u) {
    __shared__ float Ws[128 * 3];
    int tid = threadIdx.x;
    for (int i = tid; i < 384; i += 256) Ws[i] = Wout[i];
    __syncthreads();
    int row = blockIdx.x * 8 + (tid >> 5);
    int lane = tid & 31;
    if (row >= NN) return;
    float4 v = loadh4(&h[(size_t)row * 128 + lane * 4]);
    int k = lane * 4;
    float a0 = v.x * Ws[k * 3 + 0] + v.y * Ws[(k + 1) * 3 + 0] +
               v.z * Ws[(k + 2) * 3 + 0] + v.w * Ws[(k + 3) * 3 + 0];
    float a1 = v.x * Ws[k * 3 + 1] + v.y * Ws[(k + 1) * 3 + 1] +
               v.z * Ws[(k + 2) * 3 + 1] + v.w * Ws[(k + 3) * 3 + 1];
    float a2 = v.x * Ws[k * 3 + 2] + v.y * Ws[(k + 1) * 3 + 2] +
               v.z * Ws[(k + 2) * 3 + 2] + v.w * Ws[(k + 3) * 3 + 2];
    for (int off = 16; off > 0; off >>= 1) {
        a0 += __shfl_down(a0, off, 32);
        a1 += __shfl_down(a1, off, 32);
        a2 += __shfl_down(a2, off, 32);
    }
    if (lane == 0) {
        u[(size_t)row * 3 + 0] = a0;
        u[(size_t)row * 3 + 1] = a1;
        u[(size_t)row * 3 + 2] = a2;
    }
}

// ---------------- final aggregate (3 ch), unscale, + bias, tanh*0.5 ----------------

__global__ void k_agg_out(const float* __restrict__ u, const int* __restrict__ row_ptr,
                          const int2* __restrict__ csr, const float* __restrict__ dinv,
                          const float* __restrict__ bout, float* __restrict__ out) {
    int node = blockIdx.x * 256 + threadIdx.x;
    if (node >= NN) return;
    float di = dinv[node], w0 = di * di;
    float s0 = u[(size_t)node * 3 + 0] * w0;
    float s1 = u[(size_t)node * 3 + 1] * w0;
    float s2 = u[(size_t)node * 3 + 2] * w0;
    float b0a = 0.f, b1a = 0.f, b2a = 0.f;
    int e = row_ptr[node];
    int e1 = row_ptr[node + 1];
    for (; e + 2 <= e1; e += 2) {
        int2 swa = csr[e], swb = csr[e + 1];
        float wa = __int_as_float(swa.y), wb = __int_as_float(swb.y);
        const float* ua = &u[(size_t)swa.x * 3];
        const float* ub = &u[(size_t)swb.x * 3];
        s0 = fmaf(ua[0], wa, s0);
        s1 = fmaf(ua[1], wa, s1);
        s2 = fmaf(ua[2], wa, s2);
        b0a = fmaf(ub[0], wb, b0a);
        b1a = fmaf(ub[1], wb, b1a);
        b2a = fmaf(ub[2], wb, b2a);
    }
    for (; e < e1; ++e) {
        int2 sw = csr[e];
        float w = __int_as_float(sw.y);
        const float* us = &u[(size_t)sw.x * 3];
        s0 = fmaf(us[0], w, s0);
        s1 = fmaf(us[1], w, s1);
        s2 = fmaf(us[2], w, s2);
    }
    out[(size_t)node * 3 + 0] = tanhf((s0 + b0a) * INVSCALE + bout[0]) * 0.5f;
    out[(size_t)node * 3 + 1] = tanhf((s1 + b1a) * INVSCALE + bout[1]) * 0.5f;
    out[(size_t)node * 3 + 2] = tanhf((s2 + b2a) * INVSCALE + bout[2]) * 0.5f;
}

// ---------------- launch ----------------

extern "C" void kernel_launch(void* const* d_in, const int* in_sizes, int n_in,
                              void* d_out, int out_size, void* d_ws, size_t ws_size,
                              hipStream_t stream) {
    const float* x        = (const float*)d_in[0];
    const int*   ei       = (const int*)d_in[1];   // int32: [2, NE] row-major
    const float* W0       = (const float*)d_in[2];
    const float* b0       = (const float*)d_in[3];
    const float* Wh       = (const float*)d_in[4];
    const float* bh       = (const float*)d_in[5];
    const float* Wout     = (const float*)d_in[6];
    const float* bout     = (const float*)d_in[7];
    float* out            = (float*)d_out;

    char* ws = (char*)d_ws;
    float*  bufA   = (float*)(ws + 0);              // u (NN x 3 fp32) + scan temps
    __half* bufB16 = (__half*)(ws + 15360000);      // NN*128 fp16
    __half* bufC16 = (__half*)(ws + 23040000);      // NN*128 fp16
    __half* x16    = (__half*)(ws + 30720000);      // NN*64 fp16 = 3,840,000 B
    __half* W0t16  = (__half*)(ws + 34560000);      // 128*64 fp16
    __half* Wht16  = (__half*)(ws + 34576384);      // 6*128*128 fp16
    float*  bs     = (float*)(ws + 34772992);       // 7*128 fp32 scaled biases
    float*  dinv   = (float*)(ws + 34776576);       // NN floats
    int*    cnt    = (int*)  (ws + 34896576);       // NN ints
    int*    row_ptr= (int*)  (ws + 35016576);       // NN+1 ints (padded)
    int*    cursor = (int*)  (ws + 35136640);       // NN ints
    int2*   csr    = (int2*) (ws + 35256640);       // NE int2 = 3,840,000 B

    int* bsum = (int*)bufA;   // NB ints (bufA unused until final stage)

    hipMemsetAsync(cnt, 0, NN * sizeof(int), stream);
    k_count<<<(NE + 255) / 256, 256, 0, stream>>>(ei, cnt, W0, Wh, b0, bh, x,
                                                  W0t16, Wht16, bs, x16);
    k_scan1<<<NB, 256, 0, stream>>>(cnt, bsum, dinv);
    k_scan3<<<NB, 256, 0, stream>>>(cnt, bsum, row_ptr, cursor);
    k_fill<<<(NE + 255) / 256, 256, 0, stream>>>(ei, dinv, cursor, csr);

    // layer 0 (fused agg+MFMA, fp16 x): h1' = fp16(lrelu((A_hat x) @ (S*W0) + S*b0))
    k_layer0<<<NN / 16, 256, 0, stream>>>(x16, row_ptr, csr, dinv, W0t16, bs, bufB16);

    // hidden layers (fused): ping-pong bufB16 <-> bufC16; 6 layers ends back in bufB16
    __half* hin = bufB16;
    __half* hout = bufC16;
    for (int i = 0; i < 6; i++) {
        k_layer_h<<<NN / 16, 256, 0, stream>>>(hin, row_ptr, csr, dinv,
                                               Wht16 + (size_t)i * 16384,
                                               bs + 128 + (size_t)i * 128, hout);
        __half* t = hin; hin = hout; hout = t;
    }

    // final: out = tanh((A_hat (h' @ Wout)) / S + bout) * 0.5
    k_out_gemm<<<(NN + 7) / 8, 256, 0, stream>>>(hin, Wout, bufA /* u' : NN x 3 */);
    k_agg_out<<<(NN + 255) / 256, 256, 0, stream>>>(bufA, row_ptr, csr, dinv, bout, out);
}

// Round 12
// 317.474 us; speedup vs baseline: 1.9124x; 1.0180x over previous
//
#include <hip/hip_runtime.h>
#include <hip/hip_fp16.h>
#include <math.h>

#define NN 30000
#define NE 480000
#define NB 118   // ceil(NN/256)
#define SCALE 512.0f
#define INVSCALE (1.0f / 512.0f)

typedef _Float16 half8 __attribute__((ext_vector_type(8)));
typedef float floatx4 __attribute__((ext_vector_type(4)));

__device__ __forceinline__ float lrelu(float v) { return v > 0.0f ? v : v * 0.02f; }

__device__ __forceinline__ float4 fma4(float4 v, float w, float4 a) {
    a.x = fmaf(v.x, w, a.x);
    a.y = fmaf(v.y, w, a.y);
    a.z = fmaf(v.z, w, a.z);
    a.w = fmaf(v.w, w, a.w);
    return a;
}

__device__ __forceinline__ float4 loadh4(const __half* p) {
    uint2 raw = *(const uint2*)p;
    float2 f0 = __half22float2(*(__half2*)&raw.x);
    float2 f1 = __half22float2(*(__half2*)&raw.y);
    return make_float4(f0.x, f0.y, f1.x, f1.y);
}

__device__ __forceinline__ void loadh8(const __half* p, float4* lo, float4* hi) {
    uint4 raw = *(const uint4*)p;
    float2 f0 = __half22float2(*(__half2*)&raw.x);
    float2 f1 = __half22float2(*(__half2*)&raw.y);
    float2 f2 = __half22float2(*(__half2*)&raw.z);
    float2 f3 = __half22float2(*(__half2*)&raw.w);
    *lo = make_float4(f0.x, f0.y, f1.x, f1.y);
    *hi = make_float4(f2.x, f2.y, f3.x, f3.y);
}

// ---------------- CSR build (+ fused weight convert + x->fp16) ----------------

__global__ void k_count(const int* __restrict__ ei, int* __restrict__ cnt,
                        const float* __restrict__ W0, const float* __restrict__ Wh,
                        const float* __restrict__ b0, const float* __restrict__ bh,
                        const float* __restrict__ x,
                        __half* __restrict__ W0t, __half* __restrict__ Wht,
                        float* __restrict__ bs, __half* __restrict__ x16) {
    int g = blockIdx.x * 256 + threadIdx.x;
    if (g < NE) atomicAdd(&cnt[ei[NE + g]], 1);
    {   // x -> fp16: 1.92M elements, 4 per thread
        float4 v = *(const float4*)&x[(size_t)g * 4];
        __half2 a = __floats2half2_rn(v.x, v.y);
        __half2 b = __floats2half2_rn(v.z, v.w);
        uint2 pk;
        pk.x = *(unsigned int*)&a;
        pk.y = *(unsigned int*)&b;
        *(uint2*)&x16[(size_t)g * 4] = pk;
    }
    if (g < 8192) {                       // W0 [64,128] -> W0t [128n][64k], *SCALE
        int k = g >> 7, n = g & 127;
        W0t[n * 64 + k] = __float2half(W0[g] * SCALE);
    } else if (g < 8192 + 98304) {        // Wh [6][128,128] -> Wht [6][128n][128k]
        int j = g - 8192;
        int l = j >> 14;
        int r = j & 16383;
        int k = r >> 7, n = r & 127;
        Wht[l * 16384 + n * 128 + k] = __float2half(Wh[j]);
    } else if (g < 8192 + 98304 + 896) {  // biases: [b0 | bh0..bh5] * SCALE
        int j = g - 8192 - 98304;
        bs[j] = (j < 128 ? b0[j] : bh[j - 128]) * SCALE;
    }
}

__global__ void k_scan1(const int* __restrict__ cnt, int* __restrict__ bsum,
                        float* __restrict__ dinv) {
    __shared__ int sd[256];
    int tid = threadIdx.x;
    int i = blockIdx.x * 256 + tid;
    int v = (i < NN) ? cnt[i] : 0;
    if (i < NN) dinv[i] = 1.0f / sqrtf((float)(v + 1));  // +1 self loop
    sd[tid] = v;
    __syncthreads();
    for (int off = 128; off > 0; off >>= 1) {
        if (tid < off) sd[tid] += sd[tid + off];
        __syncthreads();
    }
    if (tid == 0) bsum[blockIdx.x] = sd[0];
}

__global__ void k_scan3(const int* __restrict__ cnt, const int* __restrict__ bsum,
                        int* __restrict__ row_ptr, int* __restrict__ cursor) {
    __shared__ int sd[256];
    __shared__ int offs[128];
    int tid = threadIdx.x;
    if (tid < 128) offs[tid] = (tid < blockIdx.x) ? bsum[tid] : 0;
    __syncthreads();
    for (int o = 64; o > 0; o >>= 1) {
        if (tid < o) offs[tid] += offs[tid + o];
        __syncthreads();
    }
    int i = blockIdx.x * 256 + tid;
    int v = (i < NN) ? cnt[i] : 0;
    sd[tid] = v;
    __syncthreads();
    for (int off = 1; off < 256; off <<= 1) {
        int t = (tid >= off) ? sd[tid - off] : 0;
        __syncthreads();
        sd[tid] += t;
        __syncthreads();
    }
    if (i < NN) {
        int excl = offs[0] + sd[tid] - v;
        row_ptr[i] = excl;
        cursor[i] = excl;
        if (i == NN - 1) row_ptr[NN] = excl + v;
    }
}

__global__ void k_fill(const int* __restrict__ ei, const float* __restrict__ dinv,
                       int* __restrict__ cursor, int2* __restrict__ csr) {
    int e = blockIdx.x * 256 + threadIdx.x;
    if (e < NE) {
        int s = ei[e];
        int d = ei[NE + e];
        int pos = atomicAdd(&cursor[d], 1);
        float w = dinv[s] * dinv[d];
        csr[pos] = make_int2(s, __float_as_int(w));
    }
}

// ================= fused layer kernels: agg -> LDS (A-fragment order) -> MFMA =================
// Block = 16 nodes (one 16-row MFMA tile), 256 threads (4 waves), 16 thr/node agg phase.
// LDS hsF[ks][quad][row16][8]: MFMA-side ds_read_b128 2-way aliased (free).
// NN % 16 == 0: no tail guards.
// // mega-kernel attempt (R11) failed: cooperative launch never ran (all-zero out).

// ---- layer 0: x16 fp16 [NN,64] -> out16 = fp16(lrelu((A_hat x) @ W0t + bias)) ----
__launch_bounds__(256)
__global__ void k_layer0(const __half* __restrict__ x, const int* __restrict__ row_ptr,
                         const int2* __restrict__ csr, const float* __restrict__ dinv,
                         const __half* __restrict__ Wt, const float* __restrict__ bias,
                         __half* __restrict__ out16) {
    __shared__ _Float16 hsF[2 * 4 * 16 * 8];  // 2 KB
    int tid = threadIdx.x;
    int node0 = blockIdx.x * 16;
    {
        int nl = tid >> 4;
        int node = node0 + nl;
        int c = (tid & 15) * 4;          // 4 fp16 ch / lane (8B loads)
        float di = dinv[node];
        float w0 = di * di;
        float4 hv = loadh4(&x[(size_t)node * 64 + c]);
        float4 acc[8];
        acc[0] = make_float4(hv.x * w0, hv.y * w0, hv.z * w0, hv.w * w0);
        #pragma unroll
        for (int j = 1; j < 8; j++) acc[j] = make_float4(0.f, 0.f, 0.f, 0.f);
        int e = row_ptr[node];
        int e1 = row_ptr[node + 1];
        for (; e + 8 <= e1; e += 8) {
            int2 sw[8];
            #pragma unroll
            for (int j = 0; j < 8; j++) sw[j] = csr[e + j];
            float4 v[8];
            #pragma unroll
            for (int j = 0; j < 8; j++) v[j] = loadh4(&x[(size_t)sw[j].x * 64 + c]);
            #pragma unroll
            for (int j = 0; j < 8; j++) acc[j] = fma4(v[j], __int_as_float(sw[j].y), acc[j]);
        }
        for (; e < e1; ++e) {
            int2 sw = csr[e];
            float4 v = loadh4(&x[(size_t)sw.x * 64 + c]);
            acc[0] = fma4(v, __int_as_float(sw.y), acc[0]);
        }
        #pragma unroll
        for (int j = 1; j < 8; j++) {
            acc[0].x += acc[j].x;
            acc[0].y += acc[j].y;
            acc[0].z += acc[j].z;
            acc[0].w += acc[j].w;
        }
        int ks = c >> 5, quad = (c >> 3) & 3, jj = c & 7;
        __half2 p0 = __floats2half2_rn(acc[0].x, acc[0].y);
        __half2 p1 = __floats2half2_rn(acc[0].z, acc[0].w);
        uint2 pk;
        pk.x = *(unsigned int*)&p0;
        pk.y = *(unsigned int*)&p1;
        *(uint2*)&hsF[((ks * 4 + quad) * 16 + nl) * 8 + jj] = pk;
    }
    __syncthreads();
    int wave = tid >> 6, lane = tid & 63, quad = lane >> 4, ln = lane & 15;
    half8 afrag[2];
    #pragma unroll
    for (int ks = 0; ks < 2; ks++)
        afrag[ks] = *(const half8*)&hsF[((ks * 4 + quad) * 16 + ln) * 8];
    #pragma unroll
    for (int tc = 0; tc < 2; tc++) {
        int tt = wave + tc * 4;
        floatx4 acc = (floatx4){0.f, 0.f, 0.f, 0.f};
        #pragma unroll
        for (int ks = 0; ks < 2; ks++) {
            half8 b = *(const half8*)&Wt[(size_t)(tt * 16 + ln) * 64 + ks * 32 + quad * 8];
            acc = __builtin_amdgcn_mfma_f32_16x16x32_f16(afrag[ks], b, acc, 0, 0, 0);
        }
        int col = tt * 16 + ln;
        float bb = bias[col];
        #pragma unroll
        for (int r = 0; r < 4; r++) {
            int row = node0 + quad * 4 + r;
            out16[(size_t)row * 128 + col] = __float2half(lrelu(acc[r] + bb));
        }
    }
}

// ---- hidden layer: h fp16 [NN,128] -> out16 = fp16(lrelu((A_hat h) @ Wt + bias)) ----
// LAST=true: instead of storing h7' to global, compute u = h7' @ Wout [16 rows x 3]
// in-block (quad shuffles + small LDS cross-wave sum). h7' round-trips through fp16
// to keep bit-parity with the stored-then-reloaded flow.
template <bool LAST>
__launch_bounds__(256)
__global__ void k_layer_h(const __half* __restrict__ h, const int* __restrict__ row_ptr,
                          const int2* __restrict__ csr, const float* __restrict__ dinv,
                          const __half* __restrict__ Wt, const float* __restrict__ bias,
                          __half* __restrict__ out16, const float* __restrict__ Wout,
                          float* __restrict__ u) {
    __shared__ _Float16 hsF[4 * 4 * 16 * 8];  // 4 KB
    __shared__ float uacc[4][16][3];          // cross-wave u partials (LAST only)
    int tid = threadIdx.x;
    int node0 = blockIdx.x * 16;
    {
        int nl = tid >> 4;
        int node = node0 + nl;
        int c = (tid & 15) * 8;      // 8 fp16 ch / lane (16B b128 loads)
        float di = dinv[node];
        float w0 = di * di;
        float4 hlo, hhi;
        loadh8(&h[(size_t)node * 128 + c], &hlo, &hhi);
        float4 acc[4][2];
        acc[0][0] = make_float4(hlo.x * w0, hlo.y * w0, hlo.z * w0, hlo.w * w0);
        acc[0][1] = make_float4(hhi.x * w0, hhi.y * w0, hhi.z * w0, hhi.w * w0);
        #pragma unroll
        for (int j = 1; j < 4; j++) {
            acc[j][0] = make_float4(0.f, 0.f, 0.f, 0.f);
            acc[j][1] = make_float4(0.f, 0.f, 0.f, 0.f);
        }
        int e = row_ptr[node];
        int e1 = row_ptr[node + 1];
        for (; e + 4 <= e1; e += 4) {
            int2 sw[4];
            #pragma unroll
            for (int j = 0; j < 4; j++) sw[j] = csr[e + j];
            float4 vlo[4], vhi[4];
            #pragma unroll
            for (int j = 0; j < 4; j++)
                loadh8(&h[(size_t)sw[j].x * 128 + c], &vlo[j], &vhi[j]);
            #pragma unroll
            for (int j = 0; j < 4; j++) {
                float w = __int_as_float(sw[j].y);
                acc[j][0] = fma4(vlo[j], w, acc[j][0]);
                acc[j][1] = fma4(vhi[j], w, acc[j][1]);
            }
        }
        for (; e < e1; ++e) {
            int2 sw = csr[e];
            float4 vlo, vhi;
            loadh8(&h[(size_t)sw.x * 128 + c], &vlo, &vhi);
            float w = __int_as_float(sw.y);
            acc[0][0] = fma4(vlo, w, acc[0][0]);
            acc[0][1] = fma4(vhi, w, acc[0][1]);
        }
        #pragma unroll
        for (int j = 1; j < 4; j++) {
            acc[0][0].x += acc[j][0].x; acc[0][0].y += acc[j][0].y;
            acc[0][0].z += acc[j][0].z; acc[0][0].w += acc[j][0].w;
            acc[0][1].x += acc[j][1].x; acc[0][1].y += acc[j][1].y;
            acc[0][1].z += acc[j][1].z; acc[0][1].w += acc[j][1].w;
        }
        int ks = c >> 5, quad = (c >> 3) & 3;
        __half2 p0 = __floats2half2_rn(acc[0][0].x, acc[0][0].y);
        __half2 p1 = __floats2half2_rn(acc[0][0].z, acc[0][0].w);
        __half2 p2 = __floats2half2_rn(acc[0][1].x, acc[0][1].y);
        __half2 p3 = __floats2half2_rn(acc[0][1].z, acc[0][1].w);
        uint4 pk;
        pk.x = *(unsigned int*)&p0;
        pk.y = *(unsigned int*)&p1;
        pk.z = *(unsigned int*)&p2;
        pk.w = *(unsigned int*)&p3;
        *(uint4*)&hsF[((ks * 4 + quad) * 16 + nl) * 8] = pk;
    }
    __syncthreads();
    int wave = tid >> 6, lane = tid & 63, quad = lane >> 4, ln = lane & 15;
    half8 afrag[4];
    #pragma unroll
    for (int ks = 0; ks < 4; ks++)
        afrag[ks] = *(const half8*)&hsF[((ks * 4 + quad) * 16 + ln) * 8];

    float up[4][3];  // per-row u partials (LAST)
    if (LAST) {
        #pragma unroll
        for (int r = 0; r < 4; r++)
            #pragma unroll
            for (int cc = 0; cc < 3; cc++) up[r][cc] = 0.f;
    }

    #pragma unroll
    for (int tc = 0; tc < 2; tc++) {
        int tt = wave + tc * 4;
        floatx4 acc = (floatx4){0.f, 0.f, 0.f, 0.f};
        #pragma unroll
        for (int ks = 0; ks < 4; ks++) {
            half8 b = *(const half8*)&Wt[(size_t)(tt * 16 + ln) * 128 + ks * 32 + quad * 8];
            acc = __builtin_amdgcn_mfma_f32_16x16x32_f16(afrag[ks], b, acc, 0, 0, 0);
        }
        int col = tt * 16 + ln;
        float bb = bias[col];
        if (LAST) {
            float w0o = Wout[col * 3 + 0];
            float w1o = Wout[col * 3 + 1];
            float w2o = Wout[col * 3 + 2];
            #pragma unroll
            for (int r = 0; r < 4; r++) {
                float hv = __half2float(__float2half(lrelu(acc[r] + bb)));
                up[r][0] = fmaf(hv, w0o, up[r][0]);
                up[r][1] = fmaf(hv, w1o, up[r][1]);
                up[r][2] = fmaf(hv, w2o, up[r][2]);
            }
        } else {
            #pragma unroll
            for (int r = 0; r < 4; r++) {
                int row = node0 + quad * 4 + r;
                out16[(size_t)row * 128 + col] = __float2half(lrelu(acc[r] + bb));
            }
        }
    }

    if (LAST) {
        // reduce over the 16 lanes of each quad (xor masks stay within the quad)
        #pragma unroll
        for (int m = 1; m < 16; m <<= 1) {
            #pragma unroll
            for (int r = 0; r < 4; r++) {
                #pragma unroll
                for (int cc = 0; cc < 3; cc++)
                    up[r][cc] += __shfl_xor(up[r][cc], m);
            }
        }
        if (ln == 0) {
            #pragma unroll
            for (int r = 0; r < 4; r++) {
                #pragma unroll
                for (int cc = 0; cc < 3; cc++)
                    uacc[wave][quad * 4 + r][cc] = up[r][cc];
            }
        }
        __syncthreads();
        if (tid < 48) {
            int row = tid / 3, cc = tid % 3;
            float s = (uacc[0][row][cc] + uacc[1][row][cc]) +
                      (uacc[2][row][cc] + uacc[3][row][cc]);
            u[(size_t)(node0 + row) * 3 + cc] = s;
        }
    }
}

// ---------------- final aggregate (3 ch), unscale, + bias, tanh*0.5 ----------------

__global__ void k_agg_out(const float* __restrict__ u, const int* __restrict__ row_ptr,
                          const int2* __restrict__ csr, const float* __restrict__ dinv,
                          const float* __restrict__ bout, float* __restrict__ out) {
    int node = blockIdx.x * 256 + threadIdx.x;
    if (node >= NN) return;
    float di = dinv[node], w0 = di * di;
    float s0 = u[(size_t)node * 3 + 0] * w0;
    float s1 = u[(size_t)node * 3 + 1] * w0;
    float s2 = u[(size_t)node * 3 + 2] * w0;
    float b0a = 0.f, b1a = 0.f, b2a = 0.f;
    int e = row_ptr[node];
    int e1 = row_ptr[node + 1];
    for (; e + 2 <= e1; e += 2) {
        int2 swa = csr[e], swb = csr[e + 1];
        float wa = __int_as_float(swa.y), wb = __int_as_float(swb.y);
        const float* ua = &u[(size_t)swa.x * 3];
        const float* ub = &u[(size_t)swb.x * 3];
        s0 = fmaf(ua[0], wa, s0);
        s1 = fmaf(ua[1], wa, s1);
        s2 = fmaf(ua[2], wa, s2);
        b0a = fmaf(ub[0], wb, b0a);
        b1a = fmaf(ub[1], wb, b1a);
        b2a = fmaf(ub[2], wb, b2a);
    }
    for (; e < e1; ++e) {
        int2 sw = csr[e];
        float w = __int_as_float(sw.y);
        const float* us = &u[(size_t)sw.x * 3];
        s0 = fmaf(us[0], w, s0);
        s1 = fmaf(us[1], w, s1);
        s2 = fmaf(us[2], w, s2);
    }
    out[(size_t)node * 3 + 0] = tanhf((s0 + b0a) * INVSCALE + bout[0]) * 0.5f;
    out[(size_t)node * 3 + 1] = tanhf((s1 + b1a) * INVSCALE + bout[1]) * 0.5f;
    out[(size_t)node * 3 + 2] = tanhf((s2 + b2a) * INVSCALE + bout[2]) * 0.5f;
}

// ---------------- launch ----------------

extern "C" void kernel_launch(void* const* d_in, const int* in_sizes, int n_in,
                              void* d_out, int out_size, void* d_ws, size_t ws_size,
                              hipStream_t stream) {
    const float* x        = (const float*)d_in[0];
    const int*   ei       = (const int*)d_in[1];   // int32: [2, NE] row-major
    const float* W0       = (const float*)d_in[2];
    const float* b0       = (const float*)d_in[3];
    const float* Wh       = (const float*)d_in[4];
    const float* bh       = (const float*)d_in[5];
    const float* Wout     = (const float*)d_in[6];
    const float* bout     = (const float*)d_in[7];
    float* out            = (float*)d_out;

    char* ws = (char*)d_ws;
    float*  bufA   = (float*)(ws + 0);              // u (NN x 3 fp32) + scan temps
    __half* bufB16 = (__half*)(ws + 15360000);      // NN*128 fp16
    __half* bufC16 = (__half*)(ws + 23040000);      // NN*128 fp16
    __half* x16    = (__half*)(ws + 30720000);      // NN*64 fp16
    __half* W0t16  = (__half*)(ws + 34560000);      // 128*64 fp16
    __half* Wht16  = (__half*)(ws + 34576384);      // 6*128*128 fp16
    float*  bs     = (float*)(ws + 34772992);       // 7*128 fp32 scaled biases
    float*  dinv   = (float*)(ws + 34776576);       // NN floats
    int*    cnt    = (int*)  (ws + 34896576);       // NN ints
    int*    row_ptr= (int*)  (ws + 35016576);       // NN+1 ints (padded)
    int*    cursor = (int*)  (ws + 35136640);       // NN ints
    int2*   csr    = (int2*) (ws + 35256640);       // NE int2

    int* bsum = (int*)bufA;   // NB ints (bufA unused until final stage)

    hipMemsetAsync(cnt, 0, NN * sizeof(int), stream);
    k_count<<<(NE + 255) / 256, 256, 0, stream>>>(ei, cnt, W0, Wh, b0, bh, x,
                                                  W0t16, Wht16, bs, x16);
    k_scan1<<<NB, 256, 0, stream>>>(cnt, bsum, dinv);
    k_scan3<<<NB, 256, 0, stream>>>(cnt, bsum, row_ptr, cursor);
    k_fill<<<(NE + 255) / 256, 256, 0, stream>>>(ei, dinv, cursor, csr);

    // layer 0 (fused agg+MFMA, fp16 x): h1' = fp16(lrelu((A_hat x) @ (S*W0) + S*b0))
    k_layer0<<<NN / 16, 256, 0, stream>>>(x16, row_ptr, csr, dinv, W0t16, bs, bufB16);

    // hidden layers 1..5 (fused agg+MFMA), ping-pong; layer 6 additionally fuses
    // the out-GEMM (u = h7' @ Wout) and skips the h7' global store.
    __half* hin = bufB16;
    __half* hout = bufC16;
    for (int i = 0; i < 5; i++) {
        k_layer_h<false><<<NN / 16, 256, 0, stream>>>(hin, row_ptr, csr, dinv,
                                                      Wht16 + (size_t)i * 16384,
                                                      bs + 128 + (size_t)i * 128, hout,
                                                      Wout, bufA);
        __half* t = hin; hin = hout; hout = t;
    }
    k_layer_h<true><<<NN / 16, 256, 0, stream>>>(hin, row_ptr, csr, dinv,
                                                 Wht16 + (size_t)5 * 16384,
                                                 bs + 128 + (size_t)5 * 128, hout,
                                                 Wout, bufA /* u' : NN x 3 */);

    // final: out = tanh((A_hat u') / S + bout) * 0.5
    k_agg_out<<<(NN + 255) / 256, 256, 0, stream>>>(bufA, row_ptr, csr, dinv, bout, out);
}